// Round 5
// baseline (2792.340 us; speedup 1.0000x reference)
//
#include <hip/hip_runtime.h>
#include <hip/hip_cooperative_groups.h>

namespace cg = cooperative_groups;

#define HH 64

// one-time: w2t[j*64+i] = w2[i*64+j]
static __global__ void k_prep_w2t(const float* __restrict__ w2, float* __restrict__ w2t){
  int t = blockIdx.x * 256 + threadIdx.x;   // 16 blocks x 256 = 4096
  w2t[t] = w2[(t & 63) * HH + (t >> 6)];
}

static __global__ void k_set_ones(unsigned char* __restrict__ p, int n){
  int i = blockIdx.x * blockDim.x + threadIdx.x;
  if (i < n) p[i] = 1;
}

// ===================== pair-MLP core (round-0, best measured) =====================
// 2 points per lane, hidden dim half-split across lane pair (l, l^32).
// LDS-broadcast weights: 8 ds_read_b128 + b2/w3 scalar loads per j.
// Measured 44us @R=129 sparse, VALUBusy 59% -- best of {LDS, SMEM, L1} feeds.
__device__ __forceinline__ void mlp_pair(
    const float* sw1,   // LDS: x[64] y[64] z[64] b1[64]
    const float* sw2t,  // LDS: 4096
    const float* __restrict__ b2, const float* __restrict__ w3,
    const float* __restrict__ b3,
    float xA, float yA, float zA, float xB, float yB, float zB,
    float& outA, float& outB)
{
  const int ibase = ((threadIdx.x & 63) >> 5) * 32;
  float h1a[32], h1b[32];
  #pragma unroll
  for (int k = 0; k < 32; k += 4){
    const float4 wx = *(const float4*)&sw1[      ibase + k];
    const float4 wy = *(const float4*)&sw1[ 64 + ibase + k];
    const float4 wz = *(const float4*)&sw1[128 + ibase + k];
    const float4 bb = *(const float4*)&sw1[192 + ibase + k];
    h1a[k+0] = fmaxf(fmaf(xA,wx.x,fmaf(yA,wy.x,fmaf(zA,wz.x,bb.x))),0.f);
    h1a[k+1] = fmaxf(fmaf(xA,wx.y,fmaf(yA,wy.y,fmaf(zA,wz.y,bb.y))),0.f);
    h1a[k+2] = fmaxf(fmaf(xA,wx.z,fmaf(yA,wy.z,fmaf(zA,wz.z,bb.z))),0.f);
    h1a[k+3] = fmaxf(fmaf(xA,wx.w,fmaf(yA,wy.w,fmaf(zA,wz.w,bb.w))),0.f);
    h1b[k+0] = fmaxf(fmaf(xB,wx.x,fmaf(yB,wy.x,fmaf(zB,wz.x,bb.x))),0.f);
    h1b[k+1] = fmaxf(fmaf(xB,wx.y,fmaf(yB,wy.y,fmaf(zB,wz.y,bb.y))),0.f);
    h1b[k+2] = fmaxf(fmaf(xB,wx.z,fmaf(yB,wy.z,fmaf(zB,wz.z,bb.z))),0.f);
    h1b[k+3] = fmaxf(fmaf(xB,wx.w,fmaf(yB,wy.w,fmaf(zB,wz.w,bb.w))),0.f);
  }
  float oa = b3[0], ob = oa;
  #pragma unroll 1
  for (int j = 0; j < HH; ++j){
    const float4* wrow = (const float4*)&sw2t[j*HH + ibase];
    float a0 = 0.f, a1 = 0.f, c0 = 0.f, c1 = 0.f;   // 4 indep FMA chains
    #pragma unroll
    for (int q = 0; q < 8; q += 2){
      const float4 w0 = wrow[q];
      const float4 w1q = wrow[q+1];
      a0 = fmaf(h1a[4*q+0], w0.x, a0);
      a0 = fmaf(h1a[4*q+1], w0.y, a0);
      a0 = fmaf(h1a[4*q+2], w0.z, a0);
      a0 = fmaf(h1a[4*q+3], w0.w, a0);
      a1 = fmaf(h1a[4*q+4], w1q.x, a1);
      a1 = fmaf(h1a[4*q+5], w1q.y, a1);
      a1 = fmaf(h1a[4*q+6], w1q.z, a1);
      a1 = fmaf(h1a[4*q+7], w1q.w, a1);
      c0 = fmaf(h1b[4*q+0], w0.x, c0);
      c0 = fmaf(h1b[4*q+1], w0.y, c0);
      c0 = fmaf(h1b[4*q+2], w0.z, c0);
      c0 = fmaf(h1b[4*q+3], w0.w, c0);
      c1 = fmaf(h1b[4*q+4], w1q.x, c1);
      c1 = fmaf(h1b[4*q+5], w1q.y, c1);
      c1 = fmaf(h1b[4*q+6], w1q.z, c1);
      c1 = fmaf(h1b[4*q+7], w1q.w, c1);
    }
    float accA = a0 + a1, accB = c0 + c1;
    accA += __shfl_xor(accA, 32);
    accB += __shfl_xor(accB, 32);
    const float bj = b2[j], wj = w3[j];
    oa = fmaf(fmaxf(accA + bj, 0.f), wj, oa);
    ob = fmaf(fmaxf(accB + bj, 0.f), wj, ob);
  }
  outA = 1.f / (1.f + expf(-oa));
  outB = 1.f / (1.f + expf(-ob));
}

__device__ __forceinline__ void pid2xyz(unsigned int pid, int R, int s,
                                        float& x, float& y, float& z){
  const float inv129x2 = 2.0f / 129.0f;
  unsigned int c = pid % (unsigned int)R, r = pid / (unsigned int)R;
  x = ((float)(c * (unsigned int)s) + 0.5f) * inv129x2 - 1.0f;
  y = ((float)((r % (unsigned int)R) * (unsigned int)s) + 0.5f) * inv129x2 - 1.0f;
  z = ((float)((r / (unsigned int)R) * (unsigned int)s) + 0.5f) * inv129x2 - 1.0f;
}

// ======================================================================
// ==================  FALLBACK: round-0 multi-kernel  ==================
// ======================================================================

#define STAGE_WEIGHTS()                                            \
  __shared__ float sw1[4*HH];                                      \
  __shared__ float sw2t[HH*HH];                                    \
  {                                                                \
    const int t0 = threadIdx.x;                                    \
    if (t0 < 3*HH) sw1[t0] = w1[t0];                               \
    else sw1[t0] = b1[t0 - 3*HH];                                  \
    const float4* s4 = (const float4*)w2t;                         \
    float4* d4 = (float4*)sw2t;                                    \
    for (int i4 = t0; i4 < HH*HH/4; i4 += 256) d4[i4] = s4[i4];    \
    __syncthreads();                                               \
  }

static __global__ __launch_bounds__(256)
__attribute__((amdgpu_waves_per_eu(4,4)))
void k_eval_mlp(
    const float* __restrict__ w1, const float* __restrict__ b1,
    const float* __restrict__ w2t, const float* __restrict__ b2,
    const float* __restrict__ w3, const float* __restrict__ b3,
    float* __restrict__ out, int R, int s)
{
  STAGE_WEIGHTS();
  const unsigned int n = (unsigned int)R * (unsigned int)R * (unsigned int)R;
  const int lane = threadIdx.x & 63;
  const int wid = threadIdx.x >> 6;
  const unsigned int base = blockIdx.x * 256u + (unsigned int)(wid * 64 + (lane & 31));
  const unsigned int pidA = base < n ? base : (n - 1u);
  const unsigned int pB = base + 32u;
  const unsigned int pidB = pB < n ? pB : (n - 1u);
  float xA,yA,zA,xB,yB,zB, oA,oB;
  pid2xyz(pidA, R, s, xA, yA, zA);
  pid2xyz(pidB, R, s, xB, yB, zB);
  mlp_pair(sw1, sw2t, b2, w3, b3, xA,yA,zA, xB,yB,zB, oA, oB);
  if ((threadIdx.x & 63) < 32){
    if (base < n) out[pidA] = oA;
    if (pB < n)   out[pidB] = oB;
  }
}

static __global__ __launch_bounds__(256)
__attribute__((amdgpu_waves_per_eu(4,4)))
void k_eval_sparse(
    const float* __restrict__ w1, const float* __restrict__ b1,
    const float* __restrict__ w2t, const float* __restrict__ b2,
    const float* __restrict__ w3, const float* __restrict__ b3,
    const int* __restrict__ idxl, const unsigned int* __restrict__ cnt,
    const float* __restrict__ occ_i,
    float* __restrict__ out, unsigned char* __restrict__ mism,
    int R, int s, unsigned int n)
{
  unsigned int count = *cnt;
  if (count > n) count = n;
  if (blockIdx.x * 256u >= count) return;
  STAGE_WEIGHTS();
  const int lane = threadIdx.x & 63;
  const int wid = threadIdx.x >> 6;
  const unsigned int slotA = blockIdx.x * 256u + (unsigned int)(wid * 64 + (lane & 31));
  const unsigned int slotB = slotA + 32u;
  const bool vA = slotA < count, vB = slotB < count;
  const unsigned int pidA = (unsigned int)idxl[vA ? slotA : 0];
  const unsigned int pidB = (unsigned int)idxl[vB ? slotB : 0];
  float xA,yA,zA,xB,yB,zB, oA,oB;
  pid2xyz(pidA, R, s, xA, yA, zA);
  pid2xyz(pidB, R, s, xB, yB, zB);
  mlp_pair(sw1, sw2t, b2, w3, b3, xA,yA,zA, xB,yB,zB, oA, oB);
  if ((threadIdx.x & 63) < 32){
    if (vA){
      out[pidA] = oA;
      mism[pidA] = ((occ_i[pidA] - 0.5f) * (oA - 0.5f) < 0.0f) ? (unsigned char)1 : (unsigned char)0;
    }
    if (vB){
      out[pidB] = oB;
      mism[pidB] = ((occ_i[pidB] - 0.5f) * (oB - 0.5f) < 0.0f) ? (unsigned char)1 : (unsigned char)0;
    }
  }
}

static __global__ __launch_bounds__(256) void k_resize_b0(
    const float* __restrict__ prev,
    const unsigned char* __restrict__ calc_prev,
    float* __restrict__ occ_i, float* __restrict__ occ_out,
    unsigned char* __restrict__ bnd0, unsigned char* __restrict__ calc_out,
    unsigned char* __restrict__ confA, unsigned char* __restrict__ confB,
    unsigned char* __restrict__ upd, int R, int Rp)
{
  const unsigned int n = (unsigned int)R * (unsigned int)R * (unsigned int)R;
  unsigned int gid = blockIdx.x * 256u + threadIdx.x;
  if (gid >= n) return;
  int c = (int)(gid % (unsigned int)R);
  unsigned int r = gid / (unsigned int)R;
  int b = (int)(r % (unsigned int)R);
  int a = (int)(r / (unsigned int)R);
  int a0 = a >> 1, da = a & 1;
  int b0i = b >> 1, db = b & 1;
  int c0 = c >> 1, dc = c & 1;
  float sum = 0.0f;
  int cnt = 0;
  const int tot = (da + 1) * (db + 1) * (dc + 1);
  for (int dz = 0; dz <= da; ++dz)
    for (int dy = 0; dy <= db; ++dy)
      for (int dx = 0; dx <= dc; ++dx){
        float v = prev[((unsigned int)(a0 + dz) * (unsigned int)Rp + (unsigned int)(b0i + dy)) * (unsigned int)Rp + (unsigned int)(c0 + dx)];
        sum += v;
        cnt += (v > 0.5f) ? 1 : 0;
      }
  float oi = sum / (float)tot;
  occ_i[gid] = oi;
  occ_out[gid] = oi;
  bnd0[gid] = (cnt > 0 && cnt < tot) ? 1 : 0;
  calc_out[gid] = ((da | db | dc) == 0)
      ? calc_prev[((unsigned int)a0 * (unsigned int)Rp + (unsigned int)b0i) * (unsigned int)Rp + (unsigned int)c0]
      : (unsigned char)0;
  confA[gid] = 0; confB[gid] = 0; upd[gid] = 0;
}

static __global__ __launch_bounds__(256) void k_resize_boundary(
    const float* __restrict__ prev, const float* __restrict__ occ_true,
    const unsigned char* __restrict__ calc_prev,
    float* __restrict__ occ_i, float* __restrict__ occ_out,
    unsigned char* __restrict__ bnd0,
    unsigned char* __restrict__ mism, unsigned char* __restrict__ calc_out,
    int R, int Rp)
{
  const unsigned int n = (unsigned int)R * (unsigned int)R * (unsigned int)R;
  unsigned int gid = blockIdx.x * 256u + threadIdx.x;
  if (gid >= n) return;
  int c = (int)(gid % (unsigned int)R);
  unsigned int r = gid / (unsigned int)R;
  int b = (int)(r % (unsigned int)R);
  int a = (int)(r / (unsigned int)R);
  int a0 = a >> 1, da = a & 1;
  int b0i = b >> 1, db = b & 1;
  int c0 = c >> 1, dc = c & 1;
  float sum = 0.0f;
  int cnt = 0;
  const int tot = (da + 1) * (db + 1) * (dc + 1);
  for (int dz = 0; dz <= da; ++dz)
    for (int dy = 0; dy <= db; ++dy)
      for (int dx = 0; dx <= dc; ++dx){
        float v = prev[((unsigned int)(a0 + dz) * (unsigned int)Rp + (unsigned int)(b0i + dy)) * (unsigned int)Rp + (unsigned int)(c0 + dx)];
        sum += v;
        cnt += (v > 0.5f) ? 1 : 0;
      }
  float oi = sum / (float)tot;
  occ_i[gid] = oi;
  occ_out[gid] = oi;
  bnd0[gid] = (cnt > 0 && cnt < tot) ? 1 : 0;
  mism[gid] = ((oi - 0.5f) * (occ_true[gid] - 0.5f) < 0.0f) ? 1 : 0;
  calc_out[gid] = ((da | db | dc) == 0)
      ? calc_prev[((unsigned int)a0 * (unsigned int)Rp + (unsigned int)b0i) * (unsigned int)Rp + (unsigned int)c0]
      : (unsigned char)0;
}

static __global__ __launch_bounds__(256) void k_dil7x(
    const unsigned char* __restrict__ in, unsigned char* __restrict__ outp, int R)
{
  const unsigned int n = (unsigned int)R * (unsigned int)R * (unsigned int)R;
  unsigned int gid = blockIdx.x * 256u + threadIdx.x;
  if (gid >= n) return;
  int c = (int)(gid % (unsigned int)R);
  int g = (int)gid;
  int m = 0;
  #pragma unroll
  for (int d = -3; d <= 3; ++d){
    int q = c + d;
    if (q >= 0 && q < R) m |= in[g + d];
  }
  outp[gid] = (unsigned char)(m ? 1 : 0);
}

static __global__ __launch_bounds__(256) void k_dil7y(
    const unsigned char* __restrict__ in, unsigned char* __restrict__ outp, int R)
{
  const unsigned int n = (unsigned int)R * (unsigned int)R * (unsigned int)R;
  unsigned int gid = blockIdx.x * 256u + threadIdx.x;
  if (gid >= n) return;
  unsigned int r = gid / (unsigned int)R;
  int b = (int)(r % (unsigned int)R);
  int g = (int)gid;
  int m = 0;
  #pragma unroll
  for (int d = -3; d <= 3; ++d){
    int q = b + d;
    if (q >= 0 && q < R) m |= in[g + d * R];
  }
  outp[gid] = (unsigned char)(m ? 1 : 0);
}

static __global__ __launch_bounds__(256) void k_dil7z_count(
    const unsigned char* __restrict__ in, unsigned char* __restrict__ outp,
    unsigned int* __restrict__ bcnt, int R)
{
  const unsigned int n = (unsigned int)R * (unsigned int)R * (unsigned int)R;
  unsigned int gid = blockIdx.x * 256u + threadIdx.x;
  int m = 0;
  if (gid < n){
    int a = (int)(gid / ((unsigned int)R * (unsigned int)R));
    int g = (int)gid;
    int RR = R * R;
    #pragma unroll
    for (int d = -3; d <= 3; ++d){
      int q = a + d;
      if (q >= 0 && q < R) m |= in[g + d * RR];
    }
    outp[gid] = (unsigned char)(m ? 1 : 0);
  }
  unsigned long long bm = __ballot(m != 0);
  __shared__ unsigned int wc[4];
  int wid = (int)(threadIdx.x >> 6);
  if ((threadIdx.x & 63u) == 0) wc[wid] = (unsigned int)__popcll(bm);
  __syncthreads();
  if (threadIdx.x == 0) bcnt[blockIdx.x] = wc[0] + wc[1] + wc[2] + wc[3];
}

static __global__ __launch_bounds__(1024) void k_scan(
    unsigned int* __restrict__ bcnt, unsigned int nb, unsigned int* __restrict__ total)
{
  __shared__ unsigned int part[1024];
  const unsigned int t = threadIdx.x;
  const unsigned int chunk = (nb + 1023u) / 1024u;
  const unsigned int beg = t * chunk;
  const unsigned int end = (beg + chunk < nb) ? (beg + chunk) : nb;
  unsigned int s = 0;
  for (unsigned int i = beg; i < end; ++i) s += bcnt[i];
  part[t] = s;
  __syncthreads();
  for (int offd = 1; offd < 1024; offd <<= 1){
    unsigned int v = (t >= (unsigned int)offd) ? part[t - offd] : 0u;
    __syncthreads();
    part[t] += v;
    __syncthreads();
  }
  unsigned int run = (t == 0) ? 0u : part[t - 1];
  for (unsigned int i = beg; i < end; ++i){
    unsigned int v = bcnt[i];
    bcnt[i] = run;
    run += v;
  }
  if (t == 1023) *total = part[1023];
}

static __global__ __launch_bounds__(256) void k_scatter(
    const unsigned char* __restrict__ cand, const unsigned int* __restrict__ boff,
    int* __restrict__ idxl, unsigned int n)
{
  unsigned int gid = blockIdx.x * 256u + threadIdx.x;
  bool pred = (gid < n) && (cand[gid] != 0);
  unsigned long long m = __ballot(pred);
  __shared__ unsigned int wbase[4];
  int wid = (int)(threadIdx.x >> 6);
  int lane = (int)(threadIdx.x & 63u);
  if (lane == 0) wbase[wid] = (unsigned int)__popcll(m);
  __syncthreads();
  if (threadIdx.x == 0){
    unsigned int b = boff[blockIdx.x];
    unsigned int t0 = wbase[0], t1 = wbase[1], t2 = wbase[2];
    wbase[0] = b; wbase[1] = b + t0; wbase[2] = b + t0 + t1; wbase[3] = b + t0 + t1 + t2;
  }
  __syncthreads();
  if (pred){
    int pre = __popcll(m & ((1ull << lane) - 1ull));
    idxl[wbase[wid] + (unsigned int)pre] = (int)gid;
  }
}

static __global__ __launch_bounds__(256) void k_dilate_sparse(
    const int* __restrict__ idxl, const unsigned int* __restrict__ cnt,
    const unsigned char* __restrict__ src, const unsigned char* __restrict__ mism,
    unsigned char* __restrict__ calc, unsigned char* __restrict__ conf_out,
    unsigned char* __restrict__ upd, int R, int final_step,
    const float* __restrict__ occ_true, float* __restrict__ occ_out,
    unsigned int n)
{
  unsigned int count = *cnt;
  if (count > n) count = n;
  for (unsigned int slot = blockIdx.x * 256u + threadIdx.x; slot < count;
       slot += gridDim.x * 256u){
    int gid = idxl[slot];
    int c = gid % R;
    int r = gid / R;
    int b = r % R;
    int a = r / R;
    int m = 0;
    for (int dz = -1; dz <= 1; ++dz){
      int az = a + dz; if (az < 0 || az >= R) continue;
      for (int dy = -1; dy <= 1; ++dy){
        int by = b + dy; if (by < 0 || by >= R) continue;
        for (int dx = -1; dx <= 1; ++dx){
          int cx = c + dx; if (cx < 0 || cx >= R) continue;
          m |= src[(az * R + by) * R + cx];
        }
      }
    }
    unsigned char nb = (m && !calc[gid]) ? (unsigned char)1 : (unsigned char)0;
    conf_out[gid] = (nb && mism[gid]) ? (unsigned char)1 : (unsigned char)0;
    unsigned char u = upd[gid];
    if (nb){ calc[gid] = 1; if (!u){ upd[gid] = 1; u = 1; } }
    if (final_step && u) occ_out[gid] = occ_true[gid];
  }
}

static __global__ __launch_bounds__(256) void k_dilate_step(
    const unsigned char* __restrict__ src, const unsigned char* __restrict__ mism,
    unsigned char* __restrict__ calc, unsigned char* __restrict__ conf_out,
    unsigned char* __restrict__ upd, int R, int first, int final_step,
    const float* __restrict__ occ_true, float* __restrict__ occ_out)
{
  const unsigned int n = (unsigned int)R * (unsigned int)R * (unsigned int)R;
  unsigned int gid = blockIdx.x * 256u + threadIdx.x;
  if (gid >= n) return;
  int c = (int)(gid % (unsigned int)R);
  unsigned int r = gid / (unsigned int)R;
  int b = (int)(r % (unsigned int)R);
  int a = (int)(r / (unsigned int)R);
  int m = 0;
  for (int dz = -1; dz <= 1; ++dz){
    int az = a + dz; if (az < 0 || az >= R) continue;
    for (int dy = -1; dy <= 1; ++dy){
      int by = b + dy; if (by < 0 || by >= R) continue;
      for (int dx = -1; dx <= 1; ++dx){
        int cx = c + dx; if (cx < 0 || cx >= R) continue;
        m |= src[((unsigned int)az * (unsigned int)R + (unsigned int)by) * (unsigned int)R + (unsigned int)cx];
      }
    }
  }
  unsigned char nb = (m && !calc[gid]) ? (unsigned char)1 : (unsigned char)0;
  if (nb) calc[gid] = 1;
  conf_out[gid] = (nb && mism[gid]) ? (unsigned char)1 : (unsigned char)0;
  unsigned char u;
  if (first){ u = nb; upd[gid] = nb; }
  else { u = upd[gid]; if (nb && !u){ upd[gid] = 1; u = 1; } }
  if (final_step && u) occ_out[gid] = occ_true[gid];
}

// ======================================================================
// =========================  MEGA (cooperative)  =======================
// ======================================================================

struct MegaP {
  const float* w1; const float* b1; const float* w2t; const float* b2;
  const float* w3; const float* b3;
  float* out; float* f_true; float* f_occi; float* f_prevA; float* f_prevB;
  int* i_idx; unsigned int* u_cnt;
  unsigned char* b_b0; unsigned char* b_mism; unsigned char* b_confA;
  unsigned char* b_confB; unsigned char* b_calcA; unsigned char* b_calcB;
  unsigned char* b_upd; unsigned char* b_cand; unsigned char* b_tmp;
};

__device__ __forceinline__ void dense_eval_phase(
    const float* sw1, const float* sw2t, const MegaP& p,
    float* outbuf, int R, int s, unsigned int n,
    unsigned int wave_id, unsigned int WAVES, int lane)
{
  for (unsigned int base0 = wave_id * 64u; base0 < n; base0 += WAVES * 64u){
    const unsigned int base = base0 + (unsigned int)(lane & 31);
    const unsigned int pidA = base < n ? base : (n - 1u);
    const unsigned int pB = base + 32u;
    const unsigned int pidB = pB < n ? pB : (n - 1u);
    float xA,yA,zA,xB,yB,zB, oA,oB;
    pid2xyz(pidA, R, s, xA, yA, zA);
    pid2xyz(pidB, R, s, xB, yB, zB);
    mlp_pair(sw1, sw2t, p.b2, p.w3, p.b3, xA,yA,zA, xB,yB,zB, oA,oB);
    if (lane < 32){
      if (base < n) outbuf[pidA] = oA;
      if (pB < n)   outbuf[pidB] = oB;
    }
  }
}

__device__ __forceinline__ void dilate_phase(
    const MegaP& p, const unsigned char* src, unsigned char* conf_out,
    unsigned char* calc, float* occ_out, int R, int final_step,
    unsigned int count, unsigned int tid, unsigned int NT)
{
  for (unsigned int slot = tid; slot < count; slot += NT){
    int gid = p.i_idx[slot];
    int c = gid % R;
    int r = gid / R;
    int b = r % R;
    int a = r / R;
    int m = 0;
    for (int dz = -1; dz <= 1; ++dz){
      int az = a + dz; if (az < 0 || az >= R) continue;
      for (int dy = -1; dy <= 1; ++dy){
        int by = b + dy; if (by < 0 || by >= R) continue;
        for (int dx = -1; dx <= 1; ++dx){
          int cx = c + dx; if (cx < 0 || cx >= R) continue;
          m |= src[(az * R + by) * R + cx];
        }
      }
    }
    unsigned char nb = (m && !calc[gid]) ? (unsigned char)1 : (unsigned char)0;
    conf_out[gid] = (nb && p.b_mism[gid]) ? (unsigned char)1 : (unsigned char)0;
    unsigned char u = p.b_upd[gid];
    if (nb){ calc[gid] = 1; if (!u){ p.b_upd[gid] = 1; u = 1; } }
    if (final_step && u) occ_out[gid] = p.f_true[gid];
  }
}

__device__ __forceinline__ void dense_dilate_phase(
    const MegaP& p, const unsigned char* src, unsigned char* conf_out,
    unsigned char* calc, float* occ_out, int R, int first, int final_step,
    unsigned int tid, unsigned int NT)
{
  const unsigned int n = (unsigned int)R * (unsigned int)R * (unsigned int)R;
  for (unsigned int gid = tid; gid < n; gid += NT){
    int c = (int)(gid % (unsigned int)R);
    unsigned int r = gid / (unsigned int)R;
    int b = (int)(r % (unsigned int)R);
    int a = (int)(r / (unsigned int)R);
    int m = 0;
    for (int dz = -1; dz <= 1; ++dz){
      int az = a + dz; if (az < 0 || az >= R) continue;
      for (int dy = -1; dy <= 1; ++dy){
        int by = b + dy; if (by < 0 || by >= R) continue;
        for (int dx = -1; dx <= 1; ++dx){
          int cx = c + dx; if (cx < 0 || cx >= R) continue;
          m |= src[((unsigned int)az * (unsigned int)R + (unsigned int)by) * (unsigned int)R + (unsigned int)cx];
        }
      }
    }
    unsigned char nb = (m && !calc[gid]) ? (unsigned char)1 : (unsigned char)0;
    if (nb) calc[gid] = 1;
    conf_out[gid] = (nb && p.b_mism[gid]) ? (unsigned char)1 : (unsigned char)0;
    unsigned char u;
    if (first){ u = nb; p.b_upd[gid] = nb; }
    else { u = p.b_upd[gid]; if (nb && !u){ p.b_upd[gid] = 1; u = 1; } }
    if (final_step && u) occ_out[gid] = p.f_true[gid];
  }
}

// Entire multi-level pipeline fused; grid.sync() between phases replaces
// ~27 kernel launches. Fully grid-stride: correct for ANY grid size, so the
// launcher clamps grid to the occupancy-API limit (rounds 3/4 failed because
// 960 blocks exceeded the cooperative co-residency check -> silent no-launch,
// out stayed zeroed, absmax = max|ref| = 0.715 bit-identical both rounds).
static __global__ __launch_bounds__(256, 4) void k_mega(MegaP p)
{
  __shared__ float sw1[4*HH];
  __shared__ float sw2t[HH*HH];
  {
    const int t0 = threadIdx.x;
    if (t0 < 3*HH) sw1[t0] = p.w1[t0];
    else if (t0 < 4*HH) sw1[t0] = p.b1[t0 - 3*HH];
    const float4* s4 = (const float4*)p.w2t;
    float4* d4 = (float4*)sw2t;
    for (int i4 = t0; i4 < HH*HH/4; i4 += 256) d4[i4] = s4[i4];
    __syncthreads();
  }
  cg::grid_group grid = cg::this_grid();
  const unsigned int NT = gridDim.x * 256u;
  const unsigned int tid = blockIdx.x * 256u + threadIdx.x;
  const int lane = threadIdx.x & 63;
  const unsigned int WAVES = gridDim.x * 4u;
  const unsigned int wave_id = blockIdx.x * 4u + (unsigned int)(threadIdx.x >> 6);

  #define GSYNC() do { __threadfence(); grid.sync(); } while(0)

  {
    const unsigned int n = 17u * 17u * 17u;
    dense_eval_phase(sw1, sw2t, p, p.f_prevA, 17, 8, n, wave_id, WAVES, lane);
    for (unsigned int g = tid; g < n; g += NT) p.b_calcA[g] = 1;
  }
  GSYNC();

  int Rp = 17;
  float* prev = p.f_prevA;
  unsigned char* calcP = p.b_calcA;
  unsigned char* calcC = p.b_calcB;
  for (int li = 1; li <= 3; ++li){
    const int R = 2 * Rp - 1;
    const int s = 128 / (R - 1);
    const unsigned int n = (unsigned int)R * (unsigned int)R * (unsigned int)R;
    float* occ_out = (li == 3) ? p.out : ((prev == p.f_prevA) ? p.f_prevB : p.f_prevA);

    if (li == 1){
      // dense path (R=33), round-0 bodies
      dense_eval_phase(sw1, sw2t, p, p.f_true, R, s, n, wave_id, WAVES, lane);
      GSYNC();
      for (unsigned int gid = tid; gid < n; gid += NT){
        int c = (int)(gid % (unsigned int)R);
        unsigned int r = gid / (unsigned int)R;
        int b = (int)(r % (unsigned int)R);
        int a = (int)(r / (unsigned int)R);
        int a0 = a >> 1, da = a & 1;
        int b0i = b >> 1, db = b & 1;
        int c0 = c >> 1, dc = c & 1;
        float sum = 0.0f;
        int cnt = 0;
        const int tot = (da + 1) * (db + 1) * (dc + 1);
        for (int dz = 0; dz <= da; ++dz)
          for (int dy = 0; dy <= db; ++dy)
            for (int dx = 0; dx <= dc; ++dx){
              float v = prev[((unsigned int)(a0 + dz) * (unsigned int)Rp + (unsigned int)(b0i + dy)) * (unsigned int)Rp + (unsigned int)(c0 + dx)];
              sum += v;
              cnt += (v > 0.5f) ? 1 : 0;
            }
        float oi = sum / (float)tot;
        p.f_occi[gid] = oi;
        occ_out[gid] = oi;
        p.b_b0[gid] = (cnt > 0 && cnt < tot) ? 1 : 0;
        p.b_mism[gid] = ((oi - 0.5f) * (p.f_true[gid] - 0.5f) < 0.0f) ? 1 : 0;
        calcC[gid] = ((da | db | dc) == 0)
            ? calcP[((unsigned int)a0 * (unsigned int)Rp + (unsigned int)b0i) * (unsigned int)Rp + (unsigned int)c0]
            : (unsigned char)0;
      }
      GSYNC();
      dense_dilate_phase(p, p.b_b0,    p.b_confA, calcC, occ_out, R, 1, 0, tid, NT);
      GSYNC();
      dense_dilate_phase(p, p.b_confA, p.b_confB, calcC, occ_out, R, 0, 0, tid, NT);
      GSYNC();
      dense_dilate_phase(p, p.b_confB, p.b_confA, calcC, occ_out, R, 0, 1, tid, NT);
      GSYNC();
    } else {
      // sparse path (R=65, 129), round-0 bodies
      for (unsigned int gid = tid; gid < n; gid += NT){
        int c = (int)(gid % (unsigned int)R);
        unsigned int r = gid / (unsigned int)R;
        int b = (int)(r % (unsigned int)R);
        int a = (int)(r / (unsigned int)R);
        int a0 = a >> 1, da = a & 1;
        int b0i = b >> 1, db = b & 1;
        int c0 = c >> 1, dc = c & 1;
        float sum = 0.0f;
        int cnt = 0;
        const int tot = (da + 1) * (db + 1) * (dc + 1);
        for (int dz = 0; dz <= da; ++dz)
          for (int dy = 0; dy <= db; ++dy)
            for (int dx = 0; dx <= dc; ++dx){
              float v = prev[((unsigned int)(a0 + dz) * (unsigned int)Rp + (unsigned int)(b0i + dy)) * (unsigned int)Rp + (unsigned int)(c0 + dx)];
              sum += v;
              cnt += (v > 0.5f) ? 1 : 0;
            }
        float oi = sum / (float)tot;
        p.f_occi[gid] = oi;
        occ_out[gid] = oi;
        p.b_b0[gid] = (cnt > 0 && cnt < tot) ? 1 : 0;
        calcC[gid] = ((da | db | dc) == 0)
            ? calcP[((unsigned int)a0 * (unsigned int)Rp + (unsigned int)b0i) * (unsigned int)Rp + (unsigned int)c0]
            : (unsigned char)0;
        p.b_confA[gid] = 0; p.b_confB[gid] = 0; p.b_upd[gid] = 0;
      }
      if (tid == 0) *p.u_cnt = 0u;
      GSYNC();

      for (unsigned int gid = tid; gid < n; gid += NT){
        int c = (int)(gid % (unsigned int)R);
        int g = (int)gid;
        int m = 0;
        #pragma unroll
        for (int d = -3; d <= 3; ++d){
          int q = c + d;
          if (q >= 0 && q < R) m |= p.b_b0[g + d];
        }
        p.b_tmp[gid] = (unsigned char)(m ? 1 : 0);
      }
      GSYNC();

      for (unsigned int gid = tid; gid < n; gid += NT){
        unsigned int r = gid / (unsigned int)R;
        int b = (int)(r % (unsigned int)R);
        int g = (int)gid;
        int m = 0;
        #pragma unroll
        for (int d = -3; d <= 3; ++d){
          int q = b + d;
          if (q >= 0 && q < R) m |= p.b_tmp[g + d * R];
        }
        p.b_cand[gid] = (unsigned char)(m ? 1 : 0);
      }
      GSYNC();

      for (unsigned int base = 0; base < n; base += NT){
        unsigned int gid = base + tid;
        int m = 0;
        if (gid < n){
          int a = (int)(gid / ((unsigned int)R * (unsigned int)R));
          int g = (int)gid;
          int RR = R * R;
          #pragma unroll
          for (int d = -3; d <= 3; ++d){
            int q = a + d;
            if (q >= 0 && q < R) m |= p.b_cand[g + d * RR];
          }
        }
        unsigned long long bm = __ballot(m != 0);
        unsigned int wbase = 0;
        if (lane == 0 && bm) wbase = atomicAdd(p.u_cnt, (unsigned int)__popcll(bm));
        wbase = __shfl(wbase, 0);
        if (m) p.i_idx[wbase + (unsigned int)__popcll(bm & ((1ull << lane) - 1ull))] = (int)gid;
      }
      GSYNC();

      {
        const unsigned int count = *p.u_cnt;
        for (unsigned int base0 = wave_id * 64u; base0 < count; base0 += WAVES * 64u){
          const unsigned int slotA = base0 + (unsigned int)(lane & 31);
          const unsigned int slotB = slotA + 32u;
          const bool vA = slotA < count, vB = slotB < count;
          const unsigned int pidA = (unsigned int)p.i_idx[vA ? slotA : (count - 1u)];
          const unsigned int pidB = (unsigned int)p.i_idx[vB ? slotB : (count - 1u)];
          float xA,yA,zA,xB,yB,zB, oA,oB;
          pid2xyz(pidA, R, s, xA, yA, zA);
          pid2xyz(pidB, R, s, xB, yB, zB);
          mlp_pair(sw1, sw2t, p.b2, p.w3, p.b3, xA,yA,zA, xB,yB,zB, oA,oB);
          if (lane < 32){
            if (vA){
              p.f_true[pidA] = oA;
              p.b_mism[pidA] = ((p.f_occi[pidA] - 0.5f) * (oA - 0.5f) < 0.0f) ? (unsigned char)1 : (unsigned char)0;
            }
            if (vB){
              p.f_true[pidB] = oB;
              p.b_mism[pidB] = ((p.f_occi[pidB] - 0.5f) * (oB - 0.5f) < 0.0f) ? (unsigned char)1 : (unsigned char)0;
            }
          }
        }
      }
      GSYNC();

      {
        const unsigned int count = *p.u_cnt;
        dilate_phase(p, p.b_b0,    p.b_confA, calcC, occ_out, R, 0, count, tid, NT);
        GSYNC();
        dilate_phase(p, p.b_confA, p.b_confB, calcC, occ_out, R, 0, count, tid, NT);
        GSYNC();
        dilate_phase(p, p.b_confB, p.b_confA, calcC, occ_out, R, 1, count, tid, NT);
        GSYNC();
      }
    }

    prev = occ_out;
    unsigned char* tmpc = calcP; calcP = calcC; calcC = tmpc;
    Rp = R;
  }
  #undef GSYNC
}

extern "C" void kernel_launch(void* const* d_in, const int* in_sizes, int n_in,
                              void* d_out, int out_size, void* d_ws, size_t ws_size,
                              hipStream_t stream)
{
  const float* w1 = (const float*)d_in[0];
  const float* b1 = (const float*)d_in[1];
  const float* w2 = (const float*)d_in[2];
  const float* b2 = (const float*)d_in[3];
  const float* w3 = (const float*)d_in[4];
  const float* b3 = (const float*)d_in[5];
  float* out = (float*)d_out;

  const int NF = 129 * 129 * 129;  // 2146689
  const int NP = 65 * 65 * 65;
  char* ws = (char*)d_ws;
  size_t off = 0;
  auto alloc = [&](size_t bytes) -> void* {
    void* p = (void*)(ws + off);
    off += (bytes + 255) & ~(size_t)255;
    return p;
  };
  float* f_true  = (float*)alloc((size_t)NF * 4);
  float* f_occi  = (float*)alloc((size_t)NF * 4);
  float* f_prevA = (float*)alloc((size_t)NP * 4);
  float* f_prevB = (float*)alloc((size_t)NP * 4);
  float* f_w2t   = (float*)alloc((size_t)HH * HH * 4);
  int*   i_idx   = (int*)alloc((size_t)NF * 4);
  unsigned int* u_cnt  = (unsigned int*)alloc(256);
  unsigned int* u_bcnt = (unsigned int*)alloc(8448 * 4);
  unsigned char* b_b0    = (unsigned char*)alloc(NF);
  unsigned char* b_mism  = (unsigned char*)alloc(NF);
  unsigned char* b_confA = (unsigned char*)alloc(NF);
  unsigned char* b_confB = (unsigned char*)alloc(NF);
  unsigned char* b_calcA = (unsigned char*)alloc(NF);
  unsigned char* b_calcB = (unsigned char*)alloc(NF);
  unsigned char* b_upd   = (unsigned char*)alloc(NF);
  unsigned char* b_cand  = (unsigned char*)alloc(NF);
  unsigned char* b_tmp   = (unsigned char*)alloc(NF);
  (void)ws_size;

  k_prep_w2t<<<16, 256, 0, stream>>>(w2, f_w2t);

  // ---- cooperative grid: clamp to what the occupancy API will admit ----
  static int coop_grid = -2;   // -2 uninit, -1 unavailable, >0 = grid size
  if (coop_grid == -2){
    int maxB = 0;
    hipError_t e = hipOccupancyMaxActiveBlocksPerMultiprocessor(
        &maxB, (const void*)k_mega, 256, 0);
    if (e == hipSuccess && maxB > 0){
      long g = (long)maxB * 256L;   // 256 CUs on MI355X
      if (g > 960) g = 960;
      coop_grid = (int)g;
    } else {
      coop_grid = -1;
    }
  }

  bool ran_coop = false;
  if (coop_grid > 0){
    MegaP hp;
    hp.w1 = w1; hp.b1 = b1; hp.w2t = f_w2t; hp.b2 = b2; hp.w3 = w3; hp.b3 = b3;
    hp.out = out; hp.f_true = f_true; hp.f_occi = f_occi;
    hp.f_prevA = f_prevA; hp.f_prevB = f_prevB;
    hp.i_idx = i_idx; hp.u_cnt = u_cnt;
    hp.b_b0 = b_b0; hp.b_mism = b_mism; hp.b_confA = b_confA; hp.b_confB = b_confB;
    hp.b_calcA = b_calcA; hp.b_calcB = b_calcB; hp.b_upd = b_upd;
    hp.b_cand = b_cand; hp.b_tmp = b_tmp;
    void* args[] = { (void*)&hp };
    hipError_t e = hipLaunchCooperativeKernel((const void*)k_mega, dim3(coop_grid),
                                              dim3(256), args, 0, stream);
    ran_coop = (e == hipSuccess);
    if (!ran_coop) coop_grid = -1;   // don't retry next call
  }

  if (!ran_coop){
    // ---------------- fallback: round-0 multi-kernel pipeline ----------------
    {
      int R = 17, s = 8;
      int n = R * R * R;
      int blocks = (n + 255) / 256;
      k_eval_mlp<<<blocks, 256, 0, stream>>>(w1, b1, f_w2t, b2, w3, b3, f_prevA, R, s);
      k_set_ones<<<blocks, 256, 0, stream>>>(b_calcA, n);
    }
    int Rp = 17;
    float* prev = f_prevA;
    unsigned char* calcP = b_calcA;
    unsigned char* calcC = b_calcB;
    for (int li = 1; li <= 3; ++li){
      int R = 2 * Rp - 1;
      int s = 128 / (R - 1);
      unsigned int n = (unsigned int)R * (unsigned int)R * (unsigned int)R;
      int blocks = (int)((n + 255u) / 256u);
      float* occ_out = (li == 3) ? out : ((prev == f_prevA) ? f_prevB : f_prevA);

      if (R == 33){
        k_eval_mlp<<<blocks, 256, 0, stream>>>(w1, b1, f_w2t, b2, w3, b3, f_true, R, s);
        k_resize_boundary<<<blocks, 256, 0, stream>>>(prev, f_true, calcP, f_occi, occ_out, b_b0, b_mism, calcC, R, Rp);
        k_dilate_step<<<blocks, 256, 0, stream>>>(b_b0,    b_mism, calcC, b_confA, b_upd, R, 1, 0, f_true, occ_out);
        k_dilate_step<<<blocks, 256, 0, stream>>>(b_confA, b_mism, calcC, b_confB, b_upd, R, 0, 0, f_true, occ_out);
        k_dilate_step<<<blocks, 256, 0, stream>>>(b_confB, b_mism, calcC, b_confA, b_upd, R, 0, 1, f_true, occ_out);
      } else {
        k_resize_b0<<<blocks, 256, 0, stream>>>(prev, calcP, f_occi, occ_out, b_b0, calcC,
                                                b_confA, b_confB, b_upd, R, Rp);
        k_dil7x<<<blocks, 256, 0, stream>>>(b_b0,  b_tmp,  R);
        k_dil7y<<<blocks, 256, 0, stream>>>(b_tmp, b_cand, R);
        k_dil7z_count<<<blocks, 256, 0, stream>>>(b_cand, b_tmp, u_bcnt, R);
        k_scan<<<1, 1024, 0, stream>>>(u_bcnt, (unsigned int)blocks, u_cnt);
        k_scatter<<<blocks, 256, 0, stream>>>(b_tmp, u_bcnt, i_idx, n);
        k_eval_sparse<<<blocks, 256, 0, stream>>>(
            w1, b1, f_w2t, b2, w3, b3, i_idx, u_cnt, f_occi, f_true, b_mism, R, s, n);
        int sblocks = blocks < 4096 ? blocks : 4096;
        k_dilate_sparse<<<sblocks, 256, 0, stream>>>(i_idx, u_cnt, b_b0,    b_mism, calcC, b_confA, b_upd, R, 0, f_true, occ_out, n);
        k_dilate_sparse<<<sblocks, 256, 0, stream>>>(i_idx, u_cnt, b_confA, b_mism, calcC, b_confB, b_upd, R, 0, f_true, occ_out, n);
        k_dilate_sparse<<<sblocks, 256, 0, stream>>>(i_idx, u_cnt, b_confB, b_mism, calcC, b_confA, b_upd, R, 1, f_true, occ_out, n);
      }

      prev = occ_out;
      unsigned char* tmpc = calcP; calcP = calcC; calcC = tmpc;
      Rp = R;
    }
  }
  (void)in_sizes; (void)n_in; (void)out_size;
}

// Round 6
// 510.994 us; speedup vs baseline: 5.4645x; 5.4645x over previous
//
#include <hip/hip_runtime.h>

#define HH 64

// one-time: w2t[j*64+i] = w2[i*64+j]
static __global__ void k_prep_w2t(const float* __restrict__ w2, float* __restrict__ w2t){
  int t = blockIdx.x * 256 + threadIdx.x;   // 16 blocks x 256 = 4096
  w2t[t] = w2[(t & 63) * HH + (t >> 6)];
}

// ===================== pair-MLP core (round-0, best measured) =====================
// 2 points per lane, hidden dim half-split across lane pair (l, l^32).
// LDS-broadcast weights. Measured 44us @R=129 sparse, VALUBusy 59% --
// best of {LDS, SMEM-scalar, L1-vector} weight feeds (rounds 0-2).
__device__ __forceinline__ void mlp_pair(
    const float* sw1,   // LDS: x[64] y[64] z[64] b1[64]
    const float* sw2t,  // LDS: 4096
    const float* __restrict__ b2, const float* __restrict__ w3,
    const float* __restrict__ b3,
    float xA, float yA, float zA, float xB, float yB, float zB,
    float& outA, float& outB)
{
  const int ibase = ((threadIdx.x & 63) >> 5) * 32;
  float h1a[32], h1b[32];
  #pragma unroll
  for (int k = 0; k < 32; k += 4){
    const float4 wx = *(const float4*)&sw1[      ibase + k];
    const float4 wy = *(const float4*)&sw1[ 64 + ibase + k];
    const float4 wz = *(const float4*)&sw1[128 + ibase + k];
    const float4 bb = *(const float4*)&sw1[192 + ibase + k];
    h1a[k+0] = fmaxf(fmaf(xA,wx.x,fmaf(yA,wy.x,fmaf(zA,wz.x,bb.x))),0.f);
    h1a[k+1] = fmaxf(fmaf(xA,wx.y,fmaf(yA,wy.y,fmaf(zA,wz.y,bb.y))),0.f);
    h1a[k+2] = fmaxf(fmaf(xA,wx.z,fmaf(yA,wy.z,fmaf(zA,wz.z,bb.z))),0.f);
    h1a[k+3] = fmaxf(fmaf(xA,wx.w,fmaf(yA,wy.w,fmaf(zA,wz.w,bb.w))),0.f);
    h1b[k+0] = fmaxf(fmaf(xB,wx.x,fmaf(yB,wy.x,fmaf(zB,wz.x,bb.x))),0.f);
    h1b[k+1] = fmaxf(fmaf(xB,wx.y,fmaf(yB,wy.y,fmaf(zB,wz.y,bb.y))),0.f);
    h1b[k+2] = fmaxf(fmaf(xB,wx.z,fmaf(yB,wy.z,fmaf(zB,wz.z,bb.z))),0.f);
    h1b[k+3] = fmaxf(fmaf(xB,wx.w,fmaf(yB,wy.w,fmaf(zB,wz.w,bb.w))),0.f);
  }
  float oa = b3[0], ob = oa;
  #pragma unroll 1
  for (int j = 0; j < HH; ++j){
    const float4* wrow = (const float4*)&sw2t[j*HH + ibase];
    float a0 = 0.f, a1 = 0.f, c0 = 0.f, c1 = 0.f;   // 4 indep FMA chains
    #pragma unroll
    for (int q = 0; q < 8; q += 2){
      const float4 w0 = wrow[q];
      const float4 w1q = wrow[q+1];
      a0 = fmaf(h1a[4*q+0], w0.x, a0);
      a0 = fmaf(h1a[4*q+1], w0.y, a0);
      a0 = fmaf(h1a[4*q+2], w0.z, a0);
      a0 = fmaf(h1a[4*q+3], w0.w, a0);
      a1 = fmaf(h1a[4*q+4], w1q.x, a1);
      a1 = fmaf(h1a[4*q+5], w1q.y, a1);
      a1 = fmaf(h1a[4*q+6], w1q.z, a1);
      a1 = fmaf(h1a[4*q+7], w1q.w, a1);
      c0 = fmaf(h1b[4*q+0], w0.x, c0);
      c0 = fmaf(h1b[4*q+1], w0.y, c0);
      c0 = fmaf(h1b[4*q+2], w0.z, c0);
      c0 = fmaf(h1b[4*q+3], w0.w, c0);
      c1 = fmaf(h1b[4*q+4], w1q.x, c1);
      c1 = fmaf(h1b[4*q+5], w1q.y, c1);
      c1 = fmaf(h1b[4*q+6], w1q.z, c1);
      c1 = fmaf(h1b[4*q+7], w1q.w, c1);
    }
    float accA = a0 + a1, accB = c0 + c1;
    accA += __shfl_xor(accA, 32);   // both halves end with the FULL sums
    accB += __shfl_xor(accB, 32);
    const float bj = b2[j], wj = w3[j];
    oa = fmaf(fmaxf(accA + bj, 0.f), wj, oa);
    ob = fmaf(fmaxf(accB + bj, 0.f), wj, ob);
  }
  outA = 1.f / (1.f + expf(-oa));
  outB = 1.f / (1.f + expf(-ob));
}

__device__ __forceinline__ void pid2xyz(unsigned int pid, int R, int s,
                                        float& x, float& y, float& z){
  const float inv129x2 = 2.0f / 129.0f;
  unsigned int c = pid % (unsigned int)R, r = pid / (unsigned int)R;
  x = ((float)(c * (unsigned int)s) + 0.5f) * inv129x2 - 1.0f;
  y = ((float)((r % (unsigned int)R) * (unsigned int)s) + 0.5f) * inv129x2 - 1.0f;
  z = ((float)((r / (unsigned int)R) * (unsigned int)s) + 0.5f) * inv129x2 - 1.0f;
}

#define STAGE_WEIGHTS()                                            \
  __shared__ float sw1[4*HH];                                      \
  __shared__ float sw2t[HH*HH];                                    \
  {                                                                \
    const int t0 = threadIdx.x;                                    \
    if (t0 < 3*HH) sw1[t0] = w1[t0];                               \
    else sw1[t0] = b1[t0 - 3*HH];                                  \
    const float4* s4 = (const float4*)w2t;                         \
    float4* d4 = (float4*)sw2t;                                    \
    for (int i4 = t0; i4 < HH*HH/4; i4 += 256) d4[i4] = s4[i4];    \
    __syncthreads();                                               \
  }

// ---- Level 0: dense eval R=17 + calc=1 (set_ones fused) ----
static __global__ __launch_bounds__(256)
__attribute__((amdgpu_waves_per_eu(4,4)))
void k_eval17(
    const float* __restrict__ w1, const float* __restrict__ b1,
    const float* __restrict__ w2t, const float* __restrict__ b2,
    const float* __restrict__ w3, const float* __restrict__ b3,
    float* __restrict__ out, unsigned char* __restrict__ calc)
{
  STAGE_WEIGHTS();
  const int R = 17, s = 8;
  const unsigned int n = 17u * 17u * 17u;
  const int lane = threadIdx.x & 63;
  const int wid = threadIdx.x >> 6;
  const unsigned int base = blockIdx.x * 256u + (unsigned int)(wid * 64 + (lane & 31));
  const unsigned int myb = (lane < 32) ? base : base + 32u;
  const unsigned int pidA = base < n ? base : (n - 1u);
  const unsigned int pB = base + 32u;
  const unsigned int pidB = pB < n ? pB : (n - 1u);
  float xA,yA,zA,xB,yB,zB, oA,oB;
  pid2xyz(pidA, R, s, xA, yA, zA);
  pid2xyz(pidB, R, s, xB, yB, zB);
  mlp_pair(sw1, sw2t, b2, w3, b3, xA,yA,zA, xB,yB,zB, oA, oB);
  const unsigned int my_pid = (lane < 32) ? pidA : pidB;
  const float my_o = (lane < 32) ? oA : oB;
  if (myb < n){ out[my_pid] = my_o; calc[my_pid] = 1; }
}

// ---- Level 1 (R=33): eval + resize + boundary + mism + calc, FUSED ----
// All per-own-gid (mism uses this thread's own f_true, held in register);
// no cross-block dependency -> legal single-kernel fusion.
static __global__ __launch_bounds__(256)
__attribute__((amdgpu_waves_per_eu(4,4)))
void k_eval_resize33(
    const float* __restrict__ w1, const float* __restrict__ b1,
    const float* __restrict__ w2t, const float* __restrict__ b2,
    const float* __restrict__ w3, const float* __restrict__ b3,
    const float* __restrict__ prev, const unsigned char* __restrict__ calc_prev,
    float* __restrict__ occ_i, float* __restrict__ occ_out,
    unsigned char* __restrict__ bnd0, unsigned char* __restrict__ mism,
    unsigned char* __restrict__ calc_out, float* __restrict__ f_true)
{
  STAGE_WEIGHTS();
  const int R = 33, s = 4, Rp = 17;
  const unsigned int n = 33u * 33u * 33u;
  const int lane = threadIdx.x & 63;
  const int wid = threadIdx.x >> 6;
  const unsigned int base = blockIdx.x * 256u + (unsigned int)(wid * 64 + (lane & 31));
  const unsigned int myb = (lane < 32) ? base : base + 32u;
  const unsigned int pidA = base < n ? base : (n - 1u);
  const unsigned int pB = base + 32u;
  const unsigned int pidB = pB < n ? pB : (n - 1u);
  float xA,yA,zA,xB,yB,zB, oA,oB;
  pid2xyz(pidA, R, s, xA, yA, zA);
  pid2xyz(pidB, R, s, xB, yB, zB);
  mlp_pair(sw1, sw2t, b2, w3, b3, xA,yA,zA, xB,yB,zB, oA, oB);
  const unsigned int gid = (lane < 32) ? pidA : pidB;
  const float my_o = (lane < 32) ? oA : oB;
  if (myb < n){
    f_true[gid] = my_o;
    int c = (int)(gid % (unsigned int)R);
    unsigned int r = gid / (unsigned int)R;
    int b = (int)(r % (unsigned int)R);
    int a = (int)(r / (unsigned int)R);
    int a0 = a >> 1, da = a & 1;
    int b0i = b >> 1, db = b & 1;
    int c0 = c >> 1, dc = c & 1;
    float sum = 0.0f;
    int cnt = 0;
    const int tot = (da + 1) * (db + 1) * (dc + 1);
    for (int dz = 0; dz <= da; ++dz)
      for (int dy = 0; dy <= db; ++dy)
        for (int dx = 0; dx <= dc; ++dx){
          float v = prev[((unsigned int)(a0 + dz) * (unsigned int)Rp + (unsigned int)(b0i + dy)) * (unsigned int)Rp + (unsigned int)(c0 + dx)];
          sum += v;
          cnt += (v > 0.5f) ? 1 : 0;
        }
    float oi = sum / (float)tot;
    occ_i[gid] = oi;
    occ_out[gid] = oi;
    bnd0[gid] = (cnt > 0 && cnt < tot) ? 1 : 0;
    mism[gid] = ((oi - 0.5f) * (my_o - 0.5f) < 0.0f) ? 1 : 0;
    calc_out[gid] = ((da | db | dc) == 0)
        ? calc_prev[((unsigned int)a0 * (unsigned int)Rp + (unsigned int)b0i) * (unsigned int)Rp + (unsigned int)c0]
        : (unsigned char)0;
  }
}

// ---- sparse levels: resize + seed + calc + zero conf/upd + zero u_cnt ----
static __global__ __launch_bounds__(256) void k_resize_b0(
    const float* __restrict__ prev,
    const unsigned char* __restrict__ calc_prev,
    float* __restrict__ occ_i, float* __restrict__ occ_out,
    unsigned char* __restrict__ bnd0, unsigned char* __restrict__ calc_out,
    unsigned char* __restrict__ confA, unsigned char* __restrict__ confB,
    unsigned char* __restrict__ upd, unsigned int* __restrict__ u_cnt,
    int R, int Rp)
{
  const unsigned int n = (unsigned int)R * (unsigned int)R * (unsigned int)R;
  unsigned int gid = blockIdx.x * 256u + threadIdx.x;
  if (gid == 0) *u_cnt = 0u;
  if (gid >= n) return;
  int c = (int)(gid % (unsigned int)R);
  unsigned int r = gid / (unsigned int)R;
  int b = (int)(r % (unsigned int)R);
  int a = (int)(r / (unsigned int)R);
  int a0 = a >> 1, da = a & 1;
  int b0i = b >> 1, db = b & 1;
  int c0 = c >> 1, dc = c & 1;
  float sum = 0.0f;
  int cnt = 0;
  const int tot = (da + 1) * (db + 1) * (dc + 1);
  for (int dz = 0; dz <= da; ++dz)
    for (int dy = 0; dy <= db; ++dy)
      for (int dx = 0; dx <= dc; ++dx){
        float v = prev[((unsigned int)(a0 + dz) * (unsigned int)Rp + (unsigned int)(b0i + dy)) * (unsigned int)Rp + (unsigned int)(c0 + dx)];
        sum += v;
        cnt += (v > 0.5f) ? 1 : 0;
      }
  float oi = sum / (float)tot;
  occ_i[gid] = oi;
  occ_out[gid] = oi;
  bnd0[gid] = (cnt > 0 && cnt < tot) ? 1 : 0;
  calc_out[gid] = ((da | db | dc) == 0)
      ? calc_prev[((unsigned int)a0 * (unsigned int)Rp + (unsigned int)b0i) * (unsigned int)Rp + (unsigned int)c0]
      : (unsigned char)0;
  confA[gid] = 0; confB[gid] = 0; upd[gid] = 0;
}

// ---- fused 7x7 x+y dilation (49 L1-hit byte loads/voxel; removes b_tmp pass) ----
static __global__ __launch_bounds__(256) void k_dil7xy(
    const unsigned char* __restrict__ in, unsigned char* __restrict__ outp, int R)
{
  const unsigned int n = (unsigned int)R * (unsigned int)R * (unsigned int)R;
  unsigned int gid = blockIdx.x * 256u + threadIdx.x;
  if (gid >= n) return;
  int c = (int)(gid % (unsigned int)R);
  unsigned int r = gid / (unsigned int)R;
  int b = (int)(r % (unsigned int)R);
  int g = (int)gid;
  int m = 0;
  #pragma unroll
  for (int dy = -3; dy <= 3; ++dy){
    int qy = b + dy;
    if (qy < 0 || qy >= R) continue;
    const unsigned char* row = in + g + dy * R;
    #pragma unroll
    for (int dx = -3; dx <= 3; ++dx){
      int qx = c + dx;
      if (qx >= 0 && qx < R) m |= row[dx];
    }
  }
  outp[gid] = (unsigned char)(m ? 1 : 0);
}

// ---- 7-wide z dilation + ballot/atomic compaction (replaces dil7z+scan+scatter).
// idxl order nondeterministic (atomic wave bases); consumers are per-gid and
// order-independent, so output is unaffected.
static __global__ __launch_bounds__(256) void k_dil7z_scat(
    const unsigned char* __restrict__ in, int* __restrict__ idxl,
    unsigned int* __restrict__ u_cnt, int R)
{
  const unsigned int n = (unsigned int)R * (unsigned int)R * (unsigned int)R;
  unsigned int gid = blockIdx.x * 256u + threadIdx.x;
  int m = 0;
  if (gid < n){
    int a = (int)(gid / ((unsigned int)R * (unsigned int)R));
    int g = (int)gid;
    int RR = R * R;
    #pragma unroll
    for (int d = -3; d <= 3; ++d){
      int q = a + d;
      if (q >= 0 && q < R) m |= in[g + d * RR];
    }
  }
  int lane = (int)(threadIdx.x & 63u);
  unsigned long long bm = __ballot(m != 0);
  unsigned int wbase = 0;
  if (lane == 0 && bm) wbase = atomicAdd(u_cnt, (unsigned int)__popcll(bm));
  wbase = __shfl(wbase, 0);
  if (m) idxl[wbase + (unsigned int)__popcll(bm & ((1ull << lane) - 1ull))] = (int)gid;
}

// ---- sparse eval + dilate-step-1 FUSED. Legal because step-1 needs only:
// b_b0 halo (prev kernel), own-gid calc/upd (resize kernel), own-gid mism
// (this thread's register). Half-wave ownership: lanes<32 own point A,
// lanes>=32 own point B (shfl_xor(32) gives both halves the full sums).
static __global__ __launch_bounds__(256)
__attribute__((amdgpu_waves_per_eu(4,4)))
void k_eval_dil1(
    const float* __restrict__ w1, const float* __restrict__ b1,
    const float* __restrict__ w2t, const float* __restrict__ b2,
    const float* __restrict__ w3, const float* __restrict__ b3,
    const int* __restrict__ idxl, const unsigned int* __restrict__ cnt,
    const float* __restrict__ occ_i,
    float* __restrict__ f_true, unsigned char* __restrict__ mism,
    const unsigned char* __restrict__ b0, unsigned char* __restrict__ calc,
    unsigned char* __restrict__ conf_out, unsigned char* __restrict__ upd,
    int R, int s, unsigned int n)
{
  unsigned int count = *cnt;
  if (count > n) count = n;               // guard vs stale ws during profiling replay
  if (blockIdx.x * 256u >= count) return; // block-uniform early exit
  STAGE_WEIGHTS();
  const int lane = threadIdx.x & 63;
  const int wid = threadIdx.x >> 6;
  const unsigned int slotA = blockIdx.x * 256u + (unsigned int)(wid * 64 + (lane & 31));
  const unsigned int slotB = slotA + 32u;
  const bool vA = slotA < count, vB = slotB < count;
  const unsigned int pidA = (unsigned int)idxl[vA ? slotA : 0];
  const unsigned int pidB = (unsigned int)idxl[vB ? slotB : 0];
  float xA,yA,zA,xB,yB,zB, oA,oB;
  pid2xyz(pidA, R, s, xA, yA, zA);
  pid2xyz(pidB, R, s, xB, yB, zB);
  mlp_pair(sw1, sw2t, b2, w3, b3, xA,yA,zA, xB,yB,zB, oA, oB);
  const bool my_v = (lane < 32) ? vA : vB;
  const unsigned int my_pid = (lane < 32) ? pidA : pidB;
  const float my_o = (lane < 32) ? oA : oB;
  if (my_v){
    f_true[my_pid] = my_o;
    const float oi = occ_i[my_pid];
    const unsigned char mm = ((oi - 0.5f) * (my_o - 0.5f) < 0.0f) ? (unsigned char)1 : (unsigned char)0;
    mism[my_pid] = mm;
    // dilate-step-1 (src = b0, final_step = 0; upd pre-zeroed in resize)
    int gid = (int)my_pid;
    int c = gid % R;
    int r = gid / R;
    int b = r % R;
    int a = r / R;
    int m = 0;
    for (int dz = -1; dz <= 1; ++dz){
      int az = a + dz; if (az < 0 || az >= R) continue;
      for (int dy = -1; dy <= 1; ++dy){
        int by = b + dy; if (by < 0 || by >= R) continue;
        for (int dx = -1; dx <= 1; ++dx){
          int cx = c + dx; if (cx < 0 || cx >= R) continue;
          m |= b0[(az * R + by) * R + cx];
        }
      }
    }
    unsigned char nb = (m && !calc[gid]) ? (unsigned char)1 : (unsigned char)0;
    conf_out[gid] = (nb && mm) ? (unsigned char)1 : (unsigned char)0;
    if (nb){ calc[gid] = 1; upd[gid] = 1; }
  }
}

// ---- sparse dilate-step (steps 2,3); final step commits occ_true where upd ----
static __global__ __launch_bounds__(256) void k_dilate_sparse(
    const int* __restrict__ idxl, const unsigned int* __restrict__ cnt,
    const unsigned char* __restrict__ src, const unsigned char* __restrict__ mism,
    unsigned char* __restrict__ calc, unsigned char* __restrict__ conf_out,
    unsigned char* __restrict__ upd, int R, int final_step,
    const float* __restrict__ occ_true, float* __restrict__ occ_out,
    unsigned int n)
{
  unsigned int count = *cnt;
  if (count > n) count = n;
  for (unsigned int slot = blockIdx.x * 256u + threadIdx.x; slot < count;
       slot += gridDim.x * 256u){
    int gid = idxl[slot];
    int c = gid % R;
    int r = gid / R;
    int b = r % R;
    int a = r / R;
    int m = 0;
    for (int dz = -1; dz <= 1; ++dz){
      int az = a + dz; if (az < 0 || az >= R) continue;
      for (int dy = -1; dy <= 1; ++dy){
        int by = b + dy; if (by < 0 || by >= R) continue;
        for (int dx = -1; dx <= 1; ++dx){
          int cx = c + dx; if (cx < 0 || cx >= R) continue;
          m |= src[(az * R + by) * R + cx];
        }
      }
    }
    unsigned char nb = (m && !calc[gid]) ? (unsigned char)1 : (unsigned char)0;
    conf_out[gid] = (nb && mism[gid]) ? (unsigned char)1 : (unsigned char)0;
    unsigned char u = upd[gid];
    if (nb){ calc[gid] = 1; if (!u){ upd[gid] = 1; u = 1; } }
    if (final_step && u) occ_out[gid] = occ_true[gid];
  }
}

// ---- dense dilate-step (R=33 path); final step commits occ_true ----
static __global__ __launch_bounds__(256) void k_dilate_step(
    const unsigned char* __restrict__ src, const unsigned char* __restrict__ mism,
    unsigned char* __restrict__ calc, unsigned char* __restrict__ conf_out,
    unsigned char* __restrict__ upd, int R, int first, int final_step,
    const float* __restrict__ occ_true, float* __restrict__ occ_out)
{
  const unsigned int n = (unsigned int)R * (unsigned int)R * (unsigned int)R;
  unsigned int gid = blockIdx.x * 256u + threadIdx.x;
  if (gid >= n) return;
  int c = (int)(gid % (unsigned int)R);
  unsigned int r = gid / (unsigned int)R;
  int b = (int)(r % (unsigned int)R);
  int a = (int)(r / (unsigned int)R);
  int m = 0;
  for (int dz = -1; dz <= 1; ++dz){
    int az = a + dz; if (az < 0 || az >= R) continue;
    for (int dy = -1; dy <= 1; ++dy){
      int by = b + dy; if (by < 0 || by >= R) continue;
      for (int dx = -1; dx <= 1; ++dx){
        int cx = c + dx; if (cx < 0 || cx >= R) continue;
        m |= src[((unsigned int)az * (unsigned int)R + (unsigned int)by) * (unsigned int)R + (unsigned int)cx];
      }
    }
  }
  unsigned char nb = (m && !calc[gid]) ? (unsigned char)1 : (unsigned char)0;
  if (nb) calc[gid] = 1;
  conf_out[gid] = (nb && mism[gid]) ? (unsigned char)1 : (unsigned char)0;
  unsigned char u;
  if (first){ u = nb; upd[gid] = nb; }
  else { u = upd[gid]; if (nb && !u){ upd[gid] = 1; u = 1; } }
  if (final_step && u) occ_out[gid] = occ_true[gid];
}

extern "C" void kernel_launch(void* const* d_in, const int* in_sizes, int n_in,
                              void* d_out, int out_size, void* d_ws, size_t ws_size,
                              hipStream_t stream)
{
  const float* w1 = (const float*)d_in[0];
  const float* b1 = (const float*)d_in[1];
  const float* w2 = (const float*)d_in[2];
  const float* b2 = (const float*)d_in[3];
  const float* w3 = (const float*)d_in[4];
  const float* b3 = (const float*)d_in[5];
  float* out = (float*)d_out;

  const int NF = 129 * 129 * 129;  // 2146689
  const int NP = 65 * 65 * 65;
  char* ws = (char*)d_ws;
  size_t off = 0;
  auto alloc = [&](size_t bytes) -> void* {
    void* p = (void*)(ws + off);
    off += (bytes + 255) & ~(size_t)255;
    return p;
  };
  float* f_true  = (float*)alloc((size_t)NF * 4);
  float* f_occi  = (float*)alloc((size_t)NF * 4);
  float* f_prevA = (float*)alloc((size_t)NP * 4);
  float* f_prevB = (float*)alloc((size_t)NP * 4);
  float* f_w2t   = (float*)alloc((size_t)HH * HH * 4);
  int*   i_idx   = (int*)alloc((size_t)NF * 4);
  unsigned int* u_cnt = (unsigned int*)alloc(256);
  unsigned char* b_b0    = (unsigned char*)alloc(NF);
  unsigned char* b_mism  = (unsigned char*)alloc(NF);
  unsigned char* b_confA = (unsigned char*)alloc(NF);
  unsigned char* b_confB = (unsigned char*)alloc(NF);
  unsigned char* b_calcA = (unsigned char*)alloc(NF);
  unsigned char* b_calcB = (unsigned char*)alloc(NF);
  unsigned char* b_upd   = (unsigned char*)alloc(NF);
  unsigned char* b_cand  = (unsigned char*)alloc(NF);
  (void)ws_size;

  k_prep_w2t<<<16, 256, 0, stream>>>(w2, f_w2t);

  // ---- Level 0 (R=17): eval + calc=1.  1 launch ----
  k_eval17<<<20, 256, 0, stream>>>(w1, b1, f_w2t, b2, w3, b3, f_prevA, b_calcA);

  // ---- Level 1 (R=33, dense): 4 launches ----
  {
    const int R = 33;
    const int blocks = (33*33*33 + 255) / 256;  // 141
    // eval + resize + boundary + mism + calc, fused
    k_eval_resize33<<<blocks, 256, 0, stream>>>(
        w1, b1, f_w2t, b2, w3, b3,
        f_prevA, b_calcA, f_occi, f_prevB, b_b0, b_mism, b_calcB, f_true);
    k_dilate_step<<<blocks, 256, 0, stream>>>(b_b0,    b_mism, b_calcB, b_confA, b_upd, R, 1, 0, f_true, f_prevB);
    k_dilate_step<<<blocks, 256, 0, stream>>>(b_confA, b_mism, b_calcB, b_confB, b_upd, R, 0, 0, f_true, f_prevB);
    k_dilate_step<<<blocks, 256, 0, stream>>>(b_confB, b_mism, b_calcB, b_confA, b_upd, R, 0, 1, f_true, f_prevB);
  }

  // ---- Level 2 (R=65, sparse): 6 launches ----
  {
    const int R = 65, s = 2, Rp = 33;
    const unsigned int n = 65u*65u*65u;
    const int blocks = (int)((n + 255u) / 256u);  // 1073
    const int sblocks = blocks < 4096 ? blocks : 4096;
    k_resize_b0<<<blocks, 256, 0, stream>>>(f_prevB, b_calcB, f_occi, f_prevA, b_b0, b_calcA,
                                            b_confA, b_confB, b_upd, u_cnt, R, Rp);
    k_dil7xy<<<blocks, 256, 0, stream>>>(b_b0, b_cand, R);
    k_dil7z_scat<<<blocks, 256, 0, stream>>>(b_cand, i_idx, u_cnt, R);
    k_eval_dil1<<<blocks, 256, 0, stream>>>(
        w1, b1, f_w2t, b2, w3, b3, i_idx, u_cnt, f_occi,
        f_true, b_mism, b_b0, b_calcA, b_confA, b_upd, R, s, n);
    k_dilate_sparse<<<sblocks, 256, 0, stream>>>(i_idx, u_cnt, b_confA, b_mism, b_calcA, b_confB, b_upd, R, 0, f_true, f_prevA, n);
    k_dilate_sparse<<<sblocks, 256, 0, stream>>>(i_idx, u_cnt, b_confB, b_mism, b_calcA, b_confA, b_upd, R, 1, f_true, f_prevA, n);
  }

  // ---- Level 3 (R=129, sparse): 6 launches ----
  {
    const int R = 129, s = 1, Rp = 65;
    const unsigned int n = 129u*129u*129u;
    const int blocks = (int)((n + 255u) / 256u);  // 8387
    const int sblocks = blocks < 4096 ? blocks : 4096;
    k_resize_b0<<<blocks, 256, 0, stream>>>(f_prevA, b_calcA, f_occi, out, b_b0, b_calcB,
                                            b_confA, b_confB, b_upd, u_cnt, R, Rp);
    k_dil7xy<<<blocks, 256, 0, stream>>>(b_b0, b_cand, R);
    k_dil7z_scat<<<blocks, 256, 0, stream>>>(b_cand, i_idx, u_cnt, R);
    k_eval_dil1<<<blocks, 256, 0, stream>>>(
        w1, b1, f_w2t, b2, w3, b3, i_idx, u_cnt, f_occi,
        f_true, b_mism, b_b0, b_calcB, b_confA, b_upd, R, s, n);
    k_dilate_sparse<<<sblocks, 256, 0, stream>>>(i_idx, u_cnt, b_confA, b_mism, b_calcB, b_confB, b_upd, R, 0, f_true, out, n);
    k_dilate_sparse<<<sblocks, 256, 0, stream>>>(i_idx, u_cnt, b_confB, b_mism, b_calcB, b_confA, b_upd, R, 1, f_true, out, n);
  }

  (void)in_sizes; (void)n_in; (void)out_size;
}

// Round 7
// 324.679 us; speedup vs baseline: 8.6003x; 1.5738x over previous
//
#include <hip/hip_runtime.h>

#define HH 64

// one-time: w2t[j*64+i] = w2[i*64+j]
static __global__ void k_prep_w2t(const float* __restrict__ w2, float* __restrict__ w2t){
  int t = blockIdx.x * 256 + threadIdx.x;   // 16 blocks x 256 = 4096
  w2t[t] = w2[(t & 63) * HH + (t >> 6)];
}

// ===================== pair-MLP core (round-0, best measured) =====================
// 2 points per lane, hidden dim half-split across lane pair (l, l^32).
// LDS-broadcast weights. Measured 44us @R=129 sparse, VALUBusy 59% --
// best of {LDS, SMEM-scalar, L1-vector} weight feeds (rounds 0-2).
__device__ __forceinline__ void mlp_pair(
    const float* sw1,   // LDS: x[64] y[64] z[64] b1[64]
    const float* sw2t,  // LDS: 4096
    const float* __restrict__ b2, const float* __restrict__ w3,
    const float* __restrict__ b3,
    float xA, float yA, float zA, float xB, float yB, float zB,
    float& outA, float& outB)
{
  const int ibase = ((threadIdx.x & 63) >> 5) * 32;
  float h1a[32], h1b[32];
  #pragma unroll
  for (int k = 0; k < 32; k += 4){
    const float4 wx = *(const float4*)&sw1[      ibase + k];
    const float4 wy = *(const float4*)&sw1[ 64 + ibase + k];
    const float4 wz = *(const float4*)&sw1[128 + ibase + k];
    const float4 bb = *(const float4*)&sw1[192 + ibase + k];
    h1a[k+0] = fmaxf(fmaf(xA,wx.x,fmaf(yA,wy.x,fmaf(zA,wz.x,bb.x))),0.f);
    h1a[k+1] = fmaxf(fmaf(xA,wx.y,fmaf(yA,wy.y,fmaf(zA,wz.y,bb.y))),0.f);
    h1a[k+2] = fmaxf(fmaf(xA,wx.z,fmaf(yA,wy.z,fmaf(zA,wz.z,bb.z))),0.f);
    h1a[k+3] = fmaxf(fmaf(xA,wx.w,fmaf(yA,wy.w,fmaf(zA,wz.w,bb.w))),0.f);
    h1b[k+0] = fmaxf(fmaf(xB,wx.x,fmaf(yB,wy.x,fmaf(zB,wz.x,bb.x))),0.f);
    h1b[k+1] = fmaxf(fmaf(xB,wx.y,fmaf(yB,wy.y,fmaf(zB,wz.y,bb.y))),0.f);
    h1b[k+2] = fmaxf(fmaf(xB,wx.z,fmaf(yB,wy.z,fmaf(zB,wz.z,bb.z))),0.f);
    h1b[k+3] = fmaxf(fmaf(xB,wx.w,fmaf(yB,wy.w,fmaf(zB,wz.w,bb.w))),0.f);
  }
  float oa = b3[0], ob = oa;
  #pragma unroll 1
  for (int j = 0; j < HH; ++j){
    const float4* wrow = (const float4*)&sw2t[j*HH + ibase];
    float a0 = 0.f, a1 = 0.f, c0 = 0.f, c1 = 0.f;   // 4 indep FMA chains
    #pragma unroll
    for (int q = 0; q < 8; q += 2){
      const float4 w0 = wrow[q];
      const float4 w1q = wrow[q+1];
      a0 = fmaf(h1a[4*q+0], w0.x, a0);
      a0 = fmaf(h1a[4*q+1], w0.y, a0);
      a0 = fmaf(h1a[4*q+2], w0.z, a0);
      a0 = fmaf(h1a[4*q+3], w0.w, a0);
      a1 = fmaf(h1a[4*q+4], w1q.x, a1);
      a1 = fmaf(h1a[4*q+5], w1q.y, a1);
      a1 = fmaf(h1a[4*q+6], w1q.z, a1);
      a1 = fmaf(h1a[4*q+7], w1q.w, a1);
      c0 = fmaf(h1b[4*q+0], w0.x, c0);
      c0 = fmaf(h1b[4*q+1], w0.y, c0);
      c0 = fmaf(h1b[4*q+2], w0.z, c0);
      c0 = fmaf(h1b[4*q+3], w0.w, c0);
      c1 = fmaf(h1b[4*q+4], w1q.x, c1);
      c1 = fmaf(h1b[4*q+5], w1q.y, c1);
      c1 = fmaf(h1b[4*q+6], w1q.z, c1);
      c1 = fmaf(h1b[4*q+7], w1q.w, c1);
    }
    float accA = a0 + a1, accB = c0 + c1;
    accA += __shfl_xor(accA, 32);   // both halves end with the FULL sums
    accB += __shfl_xor(accB, 32);
    const float bj = b2[j], wj = w3[j];
    oa = fmaf(fmaxf(accA + bj, 0.f), wj, oa);
    ob = fmaf(fmaxf(accB + bj, 0.f), wj, ob);
  }
  outA = 1.f / (1.f + expf(-oa));
  outB = 1.f / (1.f + expf(-ob));
}

__device__ __forceinline__ void pid2xyz(unsigned int pid, int R, int s,
                                        float& x, float& y, float& z){
  const float inv129x2 = 2.0f / 129.0f;
  unsigned int c = pid % (unsigned int)R, r = pid / (unsigned int)R;
  x = ((float)(c * (unsigned int)s) + 0.5f) * inv129x2 - 1.0f;
  y = ((float)((r % (unsigned int)R) * (unsigned int)s) + 0.5f) * inv129x2 - 1.0f;
  z = ((float)((r / (unsigned int)R) * (unsigned int)s) + 0.5f) * inv129x2 - 1.0f;
}

#define STAGE_WEIGHTS()                                            \
  __shared__ float sw1[4*HH];                                      \
  __shared__ float sw2t[HH*HH];                                    \
  {                                                                \
    const int t0 = threadIdx.x;                                    \
    if (t0 < 3*HH) sw1[t0] = w1[t0];                               \
    else sw1[t0] = b1[t0 - 3*HH];                                  \
    const float4* s4 = (const float4*)w2t;                         \
    float4* d4 = (float4*)sw2t;                                    \
    for (int i4 = t0; i4 < HH*HH/4; i4 += 256) d4[i4] = s4[i4];    \
    __syncthreads();                                               \
  }

// ---- Level 0: dense eval R=17 + calc=1 (set_ones fused; validated round 6) ----
static __global__ __launch_bounds__(256)
__attribute__((amdgpu_waves_per_eu(4,4)))
void k_eval17(
    const float* __restrict__ w1, const float* __restrict__ b1,
    const float* __restrict__ w2t, const float* __restrict__ b2,
    const float* __restrict__ w3, const float* __restrict__ b3,
    float* __restrict__ out, unsigned char* __restrict__ calc)
{
  STAGE_WEIGHTS();
  const int R = 17, s = 8;
  const unsigned int n = 17u * 17u * 17u;
  const int lane = threadIdx.x & 63;
  const int wid = threadIdx.x >> 6;
  const unsigned int base = blockIdx.x * 256u + (unsigned int)(wid * 64 + (lane & 31));
  const unsigned int myb = (lane < 32) ? base : base + 32u;
  const unsigned int pidA = base < n ? base : (n - 1u);
  const unsigned int pB = base + 32u;
  const unsigned int pidB = pB < n ? pB : (n - 1u);
  float xA,yA,zA,xB,yB,zB, oA,oB;
  pid2xyz(pidA, R, s, xA, yA, zA);
  pid2xyz(pidB, R, s, xB, yB, zB);
  mlp_pair(sw1, sw2t, b2, w3, b3, xA,yA,zA, xB,yB,zB, oA, oB);
  const unsigned int my_pid = (lane < 32) ? pidA : pidB;
  const float my_o = (lane < 32) ? oA : oB;
  if (myb < n){ out[my_pid] = my_o; calc[my_pid] = 1; }
}

// ---- Level 1 (R=33): eval + resize + boundary + mism + calc, FUSED (validated r6) ----
static __global__ __launch_bounds__(256)
__attribute__((amdgpu_waves_per_eu(4,4)))
void k_eval_resize33(
    const float* __restrict__ w1, const float* __restrict__ b1,
    const float* __restrict__ w2t, const float* __restrict__ b2,
    const float* __restrict__ w3, const float* __restrict__ b3,
    const float* __restrict__ prev, const unsigned char* __restrict__ calc_prev,
    float* __restrict__ occ_i, float* __restrict__ occ_out,
    unsigned char* __restrict__ bnd0, unsigned char* __restrict__ mism,
    unsigned char* __restrict__ calc_out, float* __restrict__ f_true)
{
  STAGE_WEIGHTS();
  const int R = 33, s = 4, Rp = 17;
  const unsigned int n = 33u * 33u * 33u;
  const int lane = threadIdx.x & 63;
  const int wid = threadIdx.x >> 6;
  const unsigned int base = blockIdx.x * 256u + (unsigned int)(wid * 64 + (lane & 31));
  const unsigned int myb = (lane < 32) ? base : base + 32u;
  const unsigned int pidA = base < n ? base : (n - 1u);
  const unsigned int pB = base + 32u;
  const unsigned int pidB = pB < n ? pB : (n - 1u);
  float xA,yA,zA,xB,yB,zB, oA,oB;
  pid2xyz(pidA, R, s, xA, yA, zA);
  pid2xyz(pidB, R, s, xB, yB, zB);
  mlp_pair(sw1, sw2t, b2, w3, b3, xA,yA,zA, xB,yB,zB, oA, oB);
  const unsigned int gid = (lane < 32) ? pidA : pidB;
  const float my_o = (lane < 32) ? oA : oB;
  if (myb < n){
    f_true[gid] = my_o;
    int c = (int)(gid % (unsigned int)R);
    unsigned int r = gid / (unsigned int)R;
    int b = (int)(r % (unsigned int)R);
    int a = (int)(r / (unsigned int)R);
    int a0 = a >> 1, da = a & 1;
    int b0i = b >> 1, db = b & 1;
    int c0 = c >> 1, dc = c & 1;
    float sum = 0.0f;
    int cnt = 0;
    const int tot = (da + 1) * (db + 1) * (dc + 1);
    for (int dz = 0; dz <= da; ++dz)
      for (int dy = 0; dy <= db; ++dy)
        for (int dx = 0; dx <= dc; ++dx){
          float v = prev[((unsigned int)(a0 + dz) * (unsigned int)Rp + (unsigned int)(b0i + dy)) * (unsigned int)Rp + (unsigned int)(c0 + dx)];
          sum += v;
          cnt += (v > 0.5f) ? 1 : 0;
        }
    float oi = sum / (float)tot;
    occ_i[gid] = oi;
    occ_out[gid] = oi;
    bnd0[gid] = (cnt > 0 && cnt < tot) ? 1 : 0;
    mism[gid] = ((oi - 0.5f) * (my_o - 0.5f) < 0.0f) ? 1 : 0;
    calc_out[gid] = ((da | db | dc) == 0)
        ? calc_prev[((unsigned int)a0 * (unsigned int)Rp + (unsigned int)b0i) * (unsigned int)Rp + (unsigned int)c0]
        : (unsigned char)0;
  }
}

// ---- sparse levels: resize + seed + calc + zero conf/upd ----
static __global__ __launch_bounds__(256) void k_resize_b0(
    const float* __restrict__ prev,
    const unsigned char* __restrict__ calc_prev,
    float* __restrict__ occ_i, float* __restrict__ occ_out,
    unsigned char* __restrict__ bnd0, unsigned char* __restrict__ calc_out,
    unsigned char* __restrict__ confA, unsigned char* __restrict__ confB,
    unsigned char* __restrict__ upd, int R, int Rp)
{
  const unsigned int n = (unsigned int)R * (unsigned int)R * (unsigned int)R;
  unsigned int gid = blockIdx.x * 256u + threadIdx.x;
  if (gid >= n) return;
  int c = (int)(gid % (unsigned int)R);
  unsigned int r = gid / (unsigned int)R;
  int b = (int)(r % (unsigned int)R);
  int a = (int)(r / (unsigned int)R);
  int a0 = a >> 1, da = a & 1;
  int b0i = b >> 1, db = b & 1;
  int c0 = c >> 1, dc = c & 1;
  float sum = 0.0f;
  int cnt = 0;
  const int tot = (da + 1) * (db + 1) * (dc + 1);
  for (int dz = 0; dz <= da; ++dz)
    for (int dy = 0; dy <= db; ++dy)
      for (int dx = 0; dx <= dc; ++dx){
        float v = prev[((unsigned int)(a0 + dz) * (unsigned int)Rp + (unsigned int)(b0i + dy)) * (unsigned int)Rp + (unsigned int)(c0 + dx)];
        sum += v;
        cnt += (v > 0.5f) ? 1 : 0;
      }
  float oi = sum / (float)tot;
  occ_i[gid] = oi;
  occ_out[gid] = oi;
  bnd0[gid] = (cnt > 0 && cnt < tot) ? 1 : 0;
  calc_out[gid] = ((da | db | dc) == 0)
      ? calc_prev[((unsigned int)a0 * (unsigned int)Rp + (unsigned int)b0i) * (unsigned int)Rp + (unsigned int)c0]
      : (unsigned char)0;
  confA[gid] = 0; confB[gid] = 0; upd[gid] = 0;
}

// ---- fused 7x7 x+y dilation (validated round 6) ----
static __global__ __launch_bounds__(256) void k_dil7xy(
    const unsigned char* __restrict__ in, unsigned char* __restrict__ outp, int R)
{
  const unsigned int n = (unsigned int)R * (unsigned int)R * (unsigned int)R;
  unsigned int gid = blockIdx.x * 256u + threadIdx.x;
  if (gid >= n) return;
  int c = (int)(gid % (unsigned int)R);
  unsigned int r = gid / (unsigned int)R;
  int b = (int)(r % (unsigned int)R);
  int g = (int)gid;
  int m = 0;
  #pragma unroll
  for (int dy = -3; dy <= 3; ++dy){
    int qy = b + dy;
    if (qy < 0 || qy >= R) continue;
    const unsigned char* row = in + g + dy * R;
    #pragma unroll
    for (int dx = -3; dx <= 3; ++dx){
      int qx = c + dx;
      if (qx >= 0 && qx < R) m |= row[dx];
    }
  }
  outp[gid] = (unsigned char)(m ? 1 : 0);
}

// ---- 7-wide z dilation + per-block count (round-0 proven path).
// Round-6 measured: fused single-atomic compaction = 175us @R=129
// (same-address device atomic ~5ns/op, serialized). Scan path ~20x cheaper.
static __global__ __launch_bounds__(256) void k_dil7z_count(
    const unsigned char* __restrict__ in, unsigned char* __restrict__ outp,
    unsigned int* __restrict__ bcnt, int R)
{
  const unsigned int n = (unsigned int)R * (unsigned int)R * (unsigned int)R;
  unsigned int gid = blockIdx.x * 256u + threadIdx.x;
  int m = 0;
  if (gid < n){
    int a = (int)(gid / ((unsigned int)R * (unsigned int)R));
    int g = (int)gid;
    int RR = R * R;
    #pragma unroll
    for (int d = -3; d <= 3; ++d){
      int q = a + d;
      if (q >= 0 && q < R) m |= in[g + d * RR];
    }
    outp[gid] = (unsigned char)(m ? 1 : 0);
  }
  unsigned long long bm = __ballot(m != 0);
  __shared__ unsigned int wc[4];
  int wid = (int)(threadIdx.x >> 6);
  if ((threadIdx.x & 63u) == 0) wc[wid] = (unsigned int)__popcll(bm);
  __syncthreads();
  if (threadIdx.x == 0) bcnt[blockIdx.x] = wc[0] + wc[1] + wc[2] + wc[3];
}

// single block, 1024 threads: exclusive scan of nb block counts (nb <= 8387)
static __global__ __launch_bounds__(1024) void k_scan(
    unsigned int* __restrict__ bcnt, unsigned int nb, unsigned int* __restrict__ total)
{
  __shared__ unsigned int part[1024];
  const unsigned int t = threadIdx.x;
  const unsigned int chunk = (nb + 1023u) / 1024u;
  const unsigned int beg = t * chunk;
  const unsigned int end = (beg + chunk < nb) ? (beg + chunk) : nb;
  unsigned int s = 0;
  for (unsigned int i = beg; i < end; ++i) s += bcnt[i];
  part[t] = s;
  __syncthreads();
  for (int offd = 1; offd < 1024; offd <<= 1){
    unsigned int v = (t >= (unsigned int)offd) ? part[t - offd] : 0u;
    __syncthreads();
    part[t] += v;
    __syncthreads();
  }
  unsigned int run = (t == 0) ? 0u : part[t - 1];
  for (unsigned int i = beg; i < end; ++i){
    unsigned int v = bcnt[i];
    bcnt[i] = run;
    run += v;
  }
  if (t == 1023) *total = part[1023];
}

static __global__ __launch_bounds__(256) void k_scatter(
    const unsigned char* __restrict__ cand, const unsigned int* __restrict__ boff,
    int* __restrict__ idxl, unsigned int n)
{
  unsigned int gid = blockIdx.x * 256u + threadIdx.x;
  bool pred = (gid < n) && (cand[gid] != 0);
  unsigned long long m = __ballot(pred);
  __shared__ unsigned int wbase[4];
  int wid = (int)(threadIdx.x >> 6);
  int lane = (int)(threadIdx.x & 63u);
  if (lane == 0) wbase[wid] = (unsigned int)__popcll(m);
  __syncthreads();
  if (threadIdx.x == 0){
    unsigned int b = boff[blockIdx.x];
    unsigned int t0 = wbase[0], t1 = wbase[1], t2 = wbase[2];
    wbase[0] = b; wbase[1] = b + t0; wbase[2] = b + t0 + t1; wbase[3] = b + t0 + t1 + t2;
  }
  __syncthreads();
  if (pred){
    int pre = __popcll(m & ((1ull << lane) - 1ull));
    idxl[wbase[wid] + (unsigned int)pre] = (int)gid;
  }
}

// ---- sparse eval + dilate-step-1 FUSED (validated round 6) ----
static __global__ __launch_bounds__(256)
__attribute__((amdgpu_waves_per_eu(4,4)))
void k_eval_dil1(
    const float* __restrict__ w1, const float* __restrict__ b1,
    const float* __restrict__ w2t, const float* __restrict__ b2,
    const float* __restrict__ w3, const float* __restrict__ b3,
    const int* __restrict__ idxl, const unsigned int* __restrict__ cnt,
    const float* __restrict__ occ_i,
    float* __restrict__ f_true, unsigned char* __restrict__ mism,
    const unsigned char* __restrict__ b0, unsigned char* __restrict__ calc,
    unsigned char* __restrict__ conf_out, unsigned char* __restrict__ upd,
    int R, int s, unsigned int n)
{
  unsigned int count = *cnt;
  if (count > n) count = n;               // guard vs stale ws during profiling replay
  if (blockIdx.x * 256u >= count) return; // block-uniform early exit
  STAGE_WEIGHTS();
  const int lane = threadIdx.x & 63;
  const int wid = threadIdx.x >> 6;
  const unsigned int slotA = blockIdx.x * 256u + (unsigned int)(wid * 64 + (lane & 31));
  const unsigned int slotB = slotA + 32u;
  const bool vA = slotA < count, vB = slotB < count;
  const unsigned int pidA = (unsigned int)idxl[vA ? slotA : 0];
  const unsigned int pidB = (unsigned int)idxl[vB ? slotB : 0];
  float xA,yA,zA,xB,yB,zB, oA,oB;
  pid2xyz(pidA, R, s, xA, yA, zA);
  pid2xyz(pidB, R, s, xB, yB, zB);
  mlp_pair(sw1, sw2t, b2, w3, b3, xA,yA,zA, xB,yB,zB, oA, oB);
  const bool my_v = (lane < 32) ? vA : vB;
  const unsigned int my_pid = (lane < 32) ? pidA : pidB;
  const float my_o = (lane < 32) ? oA : oB;
  if (my_v){
    f_true[my_pid] = my_o;
    const float oi = occ_i[my_pid];
    const unsigned char mm = ((oi - 0.5f) * (my_o - 0.5f) < 0.0f) ? (unsigned char)1 : (unsigned char)0;
    mism[my_pid] = mm;
    int gid = (int)my_pid;
    int c = gid % R;
    int r = gid / R;
    int b = r % R;
    int a = r / R;
    int m = 0;
    for (int dz = -1; dz <= 1; ++dz){
      int az = a + dz; if (az < 0 || az >= R) continue;
      for (int dy = -1; dy <= 1; ++dy){
        int by = b + dy; if (by < 0 || by >= R) continue;
        for (int dx = -1; dx <= 1; ++dx){
          int cx = c + dx; if (cx < 0 || cx >= R) continue;
          m |= b0[(az * R + by) * R + cx];
        }
      }
    }
    unsigned char nb = (m && !calc[gid]) ? (unsigned char)1 : (unsigned char)0;
    conf_out[gid] = (nb && mm) ? (unsigned char)1 : (unsigned char)0;
    if (nb){ calc[gid] = 1; upd[gid] = 1; }
  }
}

// ---- sparse dilate-step (steps 2,3); final step commits occ_true where upd ----
static __global__ __launch_bounds__(256) void k_dilate_sparse(
    const int* __restrict__ idxl, const unsigned int* __restrict__ cnt,
    const unsigned char* __restrict__ src, const unsigned char* __restrict__ mism,
    unsigned char* __restrict__ calc, unsigned char* __restrict__ conf_out,
    unsigned char* __restrict__ upd, int R, int final_step,
    const float* __restrict__ occ_true, float* __restrict__ occ_out,
    unsigned int n)
{
  unsigned int count = *cnt;
  if (count > n) count = n;
  for (unsigned int slot = blockIdx.x * 256u + threadIdx.x; slot < count;
       slot += gridDim.x * 256u){
    int gid = idxl[slot];
    int c = gid % R;
    int r = gid / R;
    int b = r % R;
    int a = r / R;
    int m = 0;
    for (int dz = -1; dz <= 1; ++dz){
      int az = a + dz; if (az < 0 || az >= R) continue;
      for (int dy = -1; dy <= 1; ++dy){
        int by = b + dy; if (by < 0 || by >= R) continue;
        for (int dx = -1; dx <= 1; ++dx){
          int cx = c + dx; if (cx < 0 || cx >= R) continue;
          m |= src[(az * R + by) * R + cx];
        }
      }
    }
    unsigned char nb = (m && !calc[gid]) ? (unsigned char)1 : (unsigned char)0;
    conf_out[gid] = (nb && mism[gid]) ? (unsigned char)1 : (unsigned char)0;
    unsigned char u = upd[gid];
    if (nb){ calc[gid] = 1; if (!u){ upd[gid] = 1; u = 1; } }
    if (final_step && u) occ_out[gid] = occ_true[gid];
  }
}

// ---- dense dilate-step (R=33 path); final step commits occ_true ----
static __global__ __launch_bounds__(256) void k_dilate_step(
    const unsigned char* __restrict__ src, const unsigned char* __restrict__ mism,
    unsigned char* __restrict__ calc, unsigned char* __restrict__ conf_out,
    unsigned char* __restrict__ upd, int R, int first, int final_step,
    const float* __restrict__ occ_true, float* __restrict__ occ_out)
{
  const unsigned int n = (unsigned int)R * (unsigned int)R * (unsigned int)R;
  unsigned int gid = blockIdx.x * 256u + threadIdx.x;
  if (gid >= n) return;
  int c = (int)(gid % (unsigned int)R);
  unsigned int r = gid / (unsigned int)R;
  int b = (int)(r % (unsigned int)R);
  int a = (int)(r / (unsigned int)R);
  int m = 0;
  for (int dz = -1; dz <= 1; ++dz){
    int az = a + dz; if (az < 0 || az >= R) continue;
    for (int dy = -1; dy <= 1; ++dy){
      int by = b + dy; if (by < 0 || by >= R) continue;
      for (int dx = -1; dx <= 1; ++dx){
        int cx = c + dx; if (cx < 0 || cx >= R) continue;
        m |= src[((unsigned int)az * (unsigned int)R + (unsigned int)by) * (unsigned int)R + (unsigned int)cx];
      }
    }
  }
  unsigned char nb = (m && !calc[gid]) ? (unsigned char)1 : (unsigned char)0;
  if (nb) calc[gid] = 1;
  conf_out[gid] = (nb && mism[gid]) ? (unsigned char)1 : (unsigned char)0;
  unsigned char u;
  if (first){ u = nb; upd[gid] = nb; }
  else { u = upd[gid]; if (nb && !u){ upd[gid] = 1; u = 1; } }
  if (final_step && u) occ_out[gid] = occ_true[gid];
}

extern "C" void kernel_launch(void* const* d_in, const int* in_sizes, int n_in,
                              void* d_out, int out_size, void* d_ws, size_t ws_size,
                              hipStream_t stream)
{
  const float* w1 = (const float*)d_in[0];
  const float* b1 = (const float*)d_in[1];
  const float* w2 = (const float*)d_in[2];
  const float* b2 = (const float*)d_in[3];
  const float* w3 = (const float*)d_in[4];
  const float* b3 = (const float*)d_in[5];
  float* out = (float*)d_out;

  const int NF = 129 * 129 * 129;  // 2146689
  const int NP = 65 * 65 * 65;
  char* ws = (char*)d_ws;
  size_t off = 0;
  auto alloc = [&](size_t bytes) -> void* {
    void* p = (void*)(ws + off);
    off += (bytes + 255) & ~(size_t)255;
    return p;
  };
  float* f_true  = (float*)alloc((size_t)NF * 4);
  float* f_occi  = (float*)alloc((size_t)NF * 4);
  float* f_prevA = (float*)alloc((size_t)NP * 4);
  float* f_prevB = (float*)alloc((size_t)NP * 4);
  float* f_w2t   = (float*)alloc((size_t)HH * HH * 4);
  int*   i_idx   = (int*)alloc((size_t)NF * 4);
  unsigned int* u_cnt  = (unsigned int*)alloc(256);
  unsigned int* u_bcnt = (unsigned int*)alloc(8448 * 4);
  unsigned char* b_b0    = (unsigned char*)alloc(NF);
  unsigned char* b_mism  = (unsigned char*)alloc(NF);
  unsigned char* b_confA = (unsigned char*)alloc(NF);
  unsigned char* b_confB = (unsigned char*)alloc(NF);
  unsigned char* b_calcA = (unsigned char*)alloc(NF);
  unsigned char* b_calcB = (unsigned char*)alloc(NF);
  unsigned char* b_upd   = (unsigned char*)alloc(NF);
  unsigned char* b_cand  = (unsigned char*)alloc(NF);
  unsigned char* b_tmp   = (unsigned char*)alloc(NF);
  (void)ws_size;

  k_prep_w2t<<<16, 256, 0, stream>>>(w2, f_w2t);

  // ---- Level 0 (R=17): eval + calc=1.  1 launch ----
  k_eval17<<<20, 256, 0, stream>>>(w1, b1, f_w2t, b2, w3, b3, f_prevA, b_calcA);

  // ---- Level 1 (R=33, dense): 4 launches ----
  {
    const int R = 33;
    const int blocks = (33*33*33 + 255) / 256;  // 141
    k_eval_resize33<<<blocks, 256, 0, stream>>>(
        w1, b1, f_w2t, b2, w3, b3,
        f_prevA, b_calcA, f_occi, f_prevB, b_b0, b_mism, b_calcB, f_true);
    k_dilate_step<<<blocks, 256, 0, stream>>>(b_b0,    b_mism, b_calcB, b_confA, b_upd, R, 1, 0, f_true, f_prevB);
    k_dilate_step<<<blocks, 256, 0, stream>>>(b_confA, b_mism, b_calcB, b_confB, b_upd, R, 0, 0, f_true, f_prevB);
    k_dilate_step<<<blocks, 256, 0, stream>>>(b_confB, b_mism, b_calcB, b_confA, b_upd, R, 0, 1, f_true, f_prevB);
  }

  // ---- Level 2 (R=65, sparse): 8 launches ----
  {
    const int R = 65, s = 2, Rp = 33;
    const unsigned int n = 65u*65u*65u;
    const int blocks = (int)((n + 255u) / 256u);  // 1073
    const int sblocks = blocks < 4096 ? blocks : 4096;
    k_resize_b0<<<blocks, 256, 0, stream>>>(f_prevB, b_calcB, f_occi, f_prevA, b_b0, b_calcA,
                                            b_confA, b_confB, b_upd, R, Rp);
    k_dil7xy<<<blocks, 256, 0, stream>>>(b_b0, b_tmp, R);
    k_dil7z_count<<<blocks, 256, 0, stream>>>(b_tmp, b_cand, u_bcnt, R);
    k_scan<<<1, 1024, 0, stream>>>(u_bcnt, (unsigned int)blocks, u_cnt);
    k_scatter<<<blocks, 256, 0, stream>>>(b_cand, u_bcnt, i_idx, n);
    k_eval_dil1<<<blocks, 256, 0, stream>>>(
        w1, b1, f_w2t, b2, w3, b3, i_idx, u_cnt, f_occi,
        f_true, b_mism, b_b0, b_calcA, b_confA, b_upd, R, s, n);
    k_dilate_sparse<<<sblocks, 256, 0, stream>>>(i_idx, u_cnt, b_confA, b_mism, b_calcA, b_confB, b_upd, R, 0, f_true, f_prevA, n);
    k_dilate_sparse<<<sblocks, 256, 0, stream>>>(i_idx, u_cnt, b_confB, b_mism, b_calcA, b_confA, b_upd, R, 1, f_true, f_prevA, n);
  }

  // ---- Level 3 (R=129, sparse): 8 launches ----
  {
    const int R = 129, s = 1, Rp = 65;
    const unsigned int n = 129u*129u*129u;
    const int blocks = (int)((n + 255u) / 256u);  // 8387
    const int sblocks = blocks < 4096 ? blocks : 4096;
    k_resize_b0<<<blocks, 256, 0, stream>>>(f_prevA, b_calcA, f_occi, out, b_b0, b_calcB,
                                            b_confA, b_confB, b_upd, R, Rp);
    k_dil7xy<<<blocks, 256, 0, stream>>>(b_b0, b_tmp, R);
    k_dil7z_count<<<blocks, 256, 0, stream>>>(b_tmp, b_cand, u_bcnt, R);
    k_scan<<<1, 1024, 0, stream>>>(u_bcnt, (unsigned int)blocks, u_cnt);
    k_scatter<<<blocks, 256, 0, stream>>>(b_cand, u_bcnt, i_idx, n);
    k_eval_dil1<<<blocks, 256, 0, stream>>>(
        w1, b1, f_w2t, b2, w3, b3, i_idx, u_cnt, f_occi,
        f_true, b_mism, b_b0, b_calcB, b_confA, b_upd, R, s, n);
    k_dilate_sparse<<<sblocks, 256, 0, stream>>>(i_idx, u_cnt, b_confA, b_mism, b_calcB, b_confB, b_upd, R, 0, f_true, out, n);
    k_dilate_sparse<<<sblocks, 256, 0, stream>>>(i_idx, u_cnt, b_confB, b_mism, b_calcB, b_confA, b_upd, R, 1, f_true, out, n);
  }

  (void)in_sizes; (void)n_in; (void)out_size;
}